// Round 17
// baseline (3591.180 us; speedup 1.0000x reference)
//
#include <hip/hip_runtime.h>

#define B_ 16
#define N_ 8192
#define S_ 2048
#define K_ 32
#define EPSBN 1e-5
#define CAP 1024

// workspace offsets (bytes)
#define OFF_PARTA    0ul            // 64*256*8 = 131072 (dead zone)
#define OFF_NEWXYZ   131072ul
#define OFF_GIDX     524288ul
#define OFF_Q1       4718592ul
#define OFF_C1       38273024ul
#define OFF_PART     46661632ul
#define OFF_AFF1     55050240ul
#define OFF_AFF2     55051264ul
#define OFF_AFF3     55052288ul
#define OFF_H3MAX    55053312ul
#define OFF_H3MIN    71830528ul
#define OFF_H2       88607744ul     // 1M*64*4 = 268435456
#define WS_NEED_H2   (OFF_H2 + 268435456ul)

#define STG(row, c) ((row)*33 + ((row)>>5) + (c))

// ---- DPP helpers: wave64 u64 reduce to lane 63 (row_shr 1/2/4/8 + row_bcast15/31) ----
template<int CTRL, int RM>
__device__ __forceinline__ unsigned long long dppmove(unsigned long long x) {
    unsigned int lo = (unsigned int)x, hi = (unsigned int)(x >> 32);
    unsigned int lo2 = (unsigned int)__builtin_amdgcn_update_dpp((int)lo, (int)lo, CTRL, RM, 0xf, false);
    unsigned int hi2 = (unsigned int)__builtin_amdgcn_update_dpp((int)hi, (int)hi, CTRL, RM, 0xf, false);
    return ((unsigned long long)hi2 << 32) | lo2;
}
__device__ __forceinline__ unsigned long long wave_max_u64(unsigned long long x) {
    unsigned long long t;
    t = dppmove<0x111, 0xf>(x); x = (t > x) ? t : x;  // row_shr:1
    t = dppmove<0x112, 0xf>(x); x = (t > x) ? t : x;  // row_shr:2
    t = dppmove<0x114, 0xf>(x); x = (t > x) ? t : x;  // row_shr:4
    t = dppmove<0x118, 0xf>(x); x = (t > x) ? t : x;  // row_shr:8
    t = dppmove<0x142, 0xa>(x); x = (t > x) ? t : x;  // row_bcast15 -> rows 1,3
    t = dppmove<0x143, 0xc>(x); x = (t > x) ? t : x;  // row_bcast31 -> rows 2,3
    return x;  // lane 63 holds the max
}
__device__ __forceinline__ unsigned long long wave_min_u64(unsigned long long x) {
    unsigned long long t;
    t = dppmove<0x111, 0xf>(x); x = (t < x) ? t : x;
    t = dppmove<0x112, 0xf>(x); x = (t < x) ? t : x;
    t = dppmove<0x114, 0xf>(x); x = (t < x) ? t : x;
    t = dppmove<0x118, 0xf>(x); x = (t < x) ? t : x;
    t = dppmove<0x142, 0xa>(x); x = (t < x) ? t : x;
    t = dppmove<0x143, 0xc>(x); x = (t < x) ? t : x;
    return x;  // lane 63 holds the min
}

// ---------------- FPS (blocks 0..15; 1 working wave/SIMD) + fused Q1 (blocks 16+) ----------------
__global__ __launch_bounds__(512) void fps_kernel(const float* __restrict__ xyz,
                                                  const float* __restrict__ pts,
                                                  const float* __restrict__ W0,
                                                  const float* __restrict__ b0,
                                                  float* __restrict__ Q1,
                                                  float* __restrict__ nxyz,
                                                  float* __restrict__ out0) {
    __shared__ float xs[N_], ys[N_], zs[N_];
    __shared__ int farHist[S_];
    __shared__ unsigned long long kq[2][4];
    int tid = threadIdx.x;
    if (blockIdx.x >= 16) {
        // ---- Q1 = W0 @ [xyz;points] + b0 (independent of FPS; fills idle CUs) ----
        int o = tid & 63, jj = tid >> 6;           // 8 points per block
        int blk = blockIdx.x - 16;                  // 0..16383
        int b = blk >> 10;
        int j = ((blk & 1023) << 3) + jj;
        const float* xb = xyz + (size_t)b * 3 * N_;
        const float* pb = pts + (size_t)b * 64 * N_;
        float acc = b0[o];
#pragma unroll
        for (int c = 0; c < 3; c++) acc += W0[o * 67 + c] * xb[c * N_ + j];
#pragma unroll 8
        for (int c = 0; c < 64; c++) acc += W0[o * 67 + 3 + c] * pb[c * N_ + j];
        Q1[(((size_t)b << 13) + j) * 64 + o] = acc;
        return;
    }
    int b = blockIdx.x;
    const float* xb = xyz + (size_t)b * 3 * N_;
    for (int i = tid; i < N_; i += 512) {
        xs[i] = xb[i]; ys[i] = xb[N_ + i]; zs[i] = xb[2 * N_ + i];
    }
    __syncthreads();
    // only threads < 256 run the FPS core: 1 working wave per SIMD (uninterleaved chain)
    float px[32], py[32], pz[32], d8[32];
    if (tid < 256) {
#pragma unroll
        for (int k = 0; k < 32; k++) {
            int i = tid + k * 256;
            px[k] = xs[i]; py[k] = ys[i]; pz[k] = zs[i];
            d8[k] = 1e10f;
        }
    }
    int far = 0;
    int w = tid >> 6;
    for (int t = 0; t < S_; t++) {
        if (tid < 256) {
            if (tid == 0) farHist[t] = far;
            float cx = xs[far], cy = ys[far], cz = zs[far];
            float bv = -1.f; int bk = 0;
#pragma unroll
            for (int k = 0; k < 32; k++) {
                float dx = px[k] - cx, dy = py[k] - cy, dz = pz[k] - cz;
                float d = dx * dx + dy * dy + dz * dz;
                float dd = fminf(d8[k], d); d8[k] = dd;
                if (dd > bv) { bv = dd; bk = k; }   // strict >: smallest k (= smallest idx) wins ties
            }
            int bi = tid + bk * 256;
            unsigned long long kk = (((unsigned long long)__float_as_uint(bv)) << 32)
                                  | (unsigned)(8191 - bi);
            kk = wave_max_u64(kk);
            if ((tid & 63) == 63) kq[t & 1][w] = kk;
        }
        __syncthreads();
        if (tid < 256) {
            int buf = t & 1;
            unsigned long long fk = kq[buf][0];
#pragma unroll
            for (int q = 1; q < 4; q++) { unsigned long long o = kq[buf][q]; fk = (o > fk) ? o : fk; }
            far = 8191 - (int)(fk & 0xffffffffull);
        }
    }
    __syncthreads();
    // fused gather: nxyz + out0
    for (int s = tid; s < S_; s += 512) {
        int idx = farHist[s];
        float x = xs[idx], y = ys[idx], z = zs[idx];
        int g = b * S_ + s;
        nxyz[g * 3 + 0] = x; nxyz[g * 3 + 1] = y; nxyz[g * 3 + 2] = z;
        out0[(b * 3 + 0) * S_ + s] = x;
        out0[(b * 3 + 1) * S_ + s] = y;
        out0[(b * 3 + 2) * S_ + s] = z;
    }
}

// ---------------- ball query: 64-thr blocks; FMA-chain distance; atomic compaction; DPP selection ----------------
__global__ __launch_bounds__(64) void ball_kernel(const float* __restrict__ xyz,
                                                  const float* __restrict__ nxyz,
                                                  int* __restrict__ gidx) {
    __shared__ unsigned long long keys[CAP];
    __shared__ int cnt;
    int bs = blockIdx.x; int b = bs >> 11; int tid = threadIdx.x;
    const float* xb = xyz + (size_t)b * 3 * N_;
    float cx = nxyz[bs * 3 + 0], cy = nxyz[bs * 3 + 1], cz = nxyz[bs * 3 + 2];
    float csq = __fadd_rn(__fadd_rn(__fmul_rn(cx, cx), __fmul_rn(cy, cy)), __fmul_rn(cz, cz));
    const float R2F = (float)(0.45 * 0.45);
    if (tid == 0) cnt = 0;
    __syncthreads();
    for (int j = tid; j < N_; j += 64) {
        float qx = xb[j], qy = xb[N_ + j], qz = xb[2 * N_ + j];
        float psq = __fadd_rn(__fadd_rn(__fmul_rn(qx, qx), __fmul_rn(qy, qy)), __fmul_rn(qz, qz));
        float t = __fmul_rn(cx, qx);
        t = __fmaf_rn(cy, qy, t);
        t = __fmaf_rn(cz, qz, t);
        float d2 = __fsub_rn(__fadd_rn(csq, psq), __fadd_rn(t, t));  // 2*t exact
        float dist = __fsqrt_rn(fmaxf(d2, 0.0f));
        if (dist < R2F) {
            int p = atomicAdd(&cnt, 1);
            if (p < CAP) keys[p] = (((unsigned long long)__float_as_uint(dist)) << 32) | (unsigned)j;
        }
    }
    __syncthreads();
    int nc = cnt; if (nc > CAP) nc = CAP;
    for (int k = 0; k < K_; k++) {
        unsigned long long bk = ~0ull;
        for (int i = tid; i < nc; i += 64) {
            unsigned long long kv = keys[i];
            bk = (kv < bk) ? kv : bk;
        }
        bk = wave_min_u64(bk);
        unsigned int lo = (unsigned int)__builtin_amdgcn_readlane((int)(unsigned int)bk, 63);
        unsigned int hi = (unsigned int)__builtin_amdgcn_readlane((int)(unsigned int)(bk >> 32), 63);
        unsigned long long mk = ((unsigned long long)hi << 32) | lo;
        int j = 0;
        if (mk != ~0ull) {
            j = (int)(mk & 0xffffffffull);
            for (int i = tid; i < nc; i += 64)
                if (keys[i] == mk) keys[i] = ~0ull;
        }
        if (tid == 0) gidx[bs * K_ + k] = j;
    }
}

// ---------------- C1 = W0[:, :3] @ centroid ----------------
__global__ __launch_bounds__(256) void c1_kernel(const float* __restrict__ nxyz,
                                                 const float* __restrict__ W0,
                                                 float* __restrict__ C1) {
    int tid = threadIdx.x; int o = tid & 63, ss = tid >> 6;
    int gs = blockIdx.x * 4 + ss;  // over B*S
    float acc = 0.f;
#pragma unroll
    for (int c = 0; c < 3; c++) acc += W0[o * 67 + c] * nxyz[gs * 3 + c];
    C1[(size_t)gs * 64 + o] = acc;
}

// ---------------- stats of h1 = Q1[g] - C1[s] ----------------
__global__ __launch_bounds__(256) void stats1_kernel(const float* __restrict__ Q1,
                                                     const float* __restrict__ C1,
                                                     const int* __restrict__ gidx,
                                                     double* __restrict__ part) {
    __shared__ double ds1[4][64], ds2[4][64];
    int tid = threadIdx.x; int o = tid & 63, ll = tid >> 6;
    double s1 = 0, s2 = 0;
    for (int it = 0; it < 256; it++) {
        int slot = it * 4096 + blockIdx.x * 4 + ll;
        int b = slot >> 16; int r = slot & 65535; int s = r >> 5;
        int g = gidx[slot];
        float q = Q1[(((size_t)b << 13) + g) * 64 + o];
        float c = C1[((size_t)(b << 11) + s) * 64 + o];
        float h = q - c;
        s1 += h; s2 += (double)h * (double)h;
    }
    ds1[ll][o] = s1; ds2[ll][o] = s2;
    __syncthreads();
    if (tid < 64) {
        double a = 0, bb = 0;
        for (int l = 0; l < 4; l++) { a += ds1[l][tid]; bb += ds2[l][tid]; }
        part[blockIdx.x * 256 + tid * 2] = a;
        part[blockIdx.x * 256 + tid * 2 + 1] = bb;
    }
}

// ---------------- stage-A reduce: 64 blocks, each sums nblocks/64 part rows ----------------
__global__ void stats_reduceA_kernel(const double* __restrict__ part, int nblocks,
                                     double* __restrict__ partA) {
    int per = nblocks >> 6;
    int a = blockIdx.x;
    int c = threadIdx.x;  // 256 threads, one column each
    double s = 0;
    for (int k = 0; k < per; k++)
        s += part[((size_t)(a * per + k)) * 256 + c];
    partA[(size_t)a * 256 + c] = s;
}

// ---------------- stage-B reduce -> affine (a, c); launch with 4*C threads ----------------
__global__ void stats_reduce_kernel(const double* __restrict__ part, int nblocks, int C,
                                    const float* __restrict__ gamma, const float* __restrict__ beta,
                                    float* __restrict__ aff) {
    __shared__ double s1s[512], s2s[512];
    int tid = threadIdx.x;
    int q = tid / C; int o = tid - q * C;
    double s1 = 0, s2 = 0;
    for (int i = q; i < nblocks; i += 4) {
        s1 += part[(size_t)i * 256 + o * 2];
        s2 += part[(size_t)i * 256 + o * 2 + 1];
    }
    s1s[tid] = s1; s2s[tid] = s2;
    __syncthreads();
    if (tid < C) {
        double a1 = s1s[tid] + s1s[tid + C] + s1s[tid + 2 * C] + s1s[tid + 3 * C];
        double a2 = s2s[tid] + s2s[tid + C] + s2s[tid + 2 * C] + s2s[tid + 3 * C];
        const double cnt = 1048576.0;
        double mean = a1 / cnt;
        double var = a2 / cnt - mean * mean; if (var < 0) var = 0;
        double a = (double)gamma[tid] / sqrt(var + EPSBN);
        double c = (double)beta[tid] - a * mean;
        aff[tid] = (float)a; aff[C + tid] = (float)c;
    }
}

// ---------------- layer2 (h2 = W1 @ relu(bn1(h1))) + stats of h2; optional h2 store ----------------
__global__ __launch_bounds__(256) void layer2_stats_kernel(const float* __restrict__ Q1,
                                                           const float* __restrict__ C1,
                                                           const int* __restrict__ gidx,
                                                           const float* __restrict__ aff1,
                                                           const float* __restrict__ W1,
                                                           const float* __restrict__ b1,
                                                           double* __restrict__ part,
                                                           float* __restrict__ h2out) {
    __shared__ __align__(16) float Wl[64 * 64];
    __shared__ float stage[256 * 33 + 8];
    __shared__ float sA[64], sC[64], sB[64];
    __shared__ double r1[8][33], r2[8][33];
    int tid = threadIdx.x;
    for (int i = tid; i < 4096; i += 256) { int o = i >> 6, c = i & 63; Wl[c * 64 + o] = W1[i]; }
    if (tid < 64) { sA[tid] = aff1[tid]; sC[tid] = aff1[64 + tid]; sB[tid] = b1[tid]; }
    __syncthreads();
    int slot = blockIdx.x * 256 + tid;
    int b = slot >> 16; int r = slot & 65535; int s = r >> 5;
    int g = gidx[slot];
    float x[64];
    {
        const float4* qp4 = (const float4*)(Q1 + (((size_t)b << 13) + g) * 64);
        const float4* cp4 = (const float4*)(C1 + ((size_t)(b << 11) + s) * 64);
#pragma unroll
        for (int c4 = 0; c4 < 16; c4++) {
            float4 q = qp4[c4], cc = cp4[c4];
            int c = c4 * 4;
            x[c + 0] = fmaxf(0.f, sA[c + 0] * (q.x - cc.x) + sC[c + 0]);
            x[c + 1] = fmaxf(0.f, sA[c + 1] * (q.y - cc.y) + sC[c + 1]);
            x[c + 2] = fmaxf(0.f, sA[c + 2] * (q.z - cc.z) + sC[c + 2]);
            x[c + 3] = fmaxf(0.f, sA[c + 3] * (q.w - cc.w) + sC[c + 3]);
        }
    }
    const float4* Wl4 = (const float4*)Wl;
    for (int ch = 0; ch < 2; ch++) {
        float acc[32];
#pragma unroll
        for (int o = 0; o < 32; o++) acc[o] = sB[ch * 32 + o];
#pragma unroll
        for (int c = 0; c < 64; c++) {
            float xv = x[c];
#pragma unroll
            for (int og = 0; og < 8; og++) {
                float4 w = Wl4[c * 16 + ch * 8 + og];
                acc[og * 4 + 0] += w.x * xv; acc[og * 4 + 1] += w.y * xv;
                acc[og * 4 + 2] += w.z * xv; acc[og * 4 + 3] += w.w * xv;
            }
        }
        if (h2out) {
            float4* o4 = (float4*)(h2out + (size_t)slot * 64 + ch * 32);
#pragma unroll
            for (int og = 0; og < 8; og++)
                o4[og] = make_float4(acc[og * 4 + 0], acc[og * 4 + 1], acc[og * 4 + 2], acc[og * 4 + 3]);
        }
#pragma unroll
        for (int o = 0; o < 32; o++) stage[STG(tid, o)] = acc[o];
        __syncthreads();
        int chn = tid & 31, rr = tid >> 5;
        double s1 = 0, s2 = 0;
        for (int row = rr * 32; row < rr * 32 + 32; row++) {
            float v = stage[STG(row, chn)];
            s1 += v; s2 += (double)v * (double)v;
        }
        r1[rr][chn] = s1; r2[rr][chn] = s2;
        __syncthreads();
        if (tid < 32) {
            double a = 0, bb = 0;
            for (int l = 0; l < 8; l++) { a += r1[l][tid]; bb += r2[l][tid]; }
            part[blockIdx.x * 256 + (ch * 32 + tid) * 2] = a;
            part[blockIdx.x * 256 + (ch * 32 + tid) * 2 + 1] = bb;
        }
        __syncthreads();
    }
}

// ---------------- layer3 (slow path): recompute h2 -> x3 -> h3; stats + per-group min/max ----------------
__global__ __launch_bounds__(256) void layer3_kernel(const float* __restrict__ Q1,
                                                     const float* __restrict__ C1,
                                                     const int* __restrict__ gidx,
                                                     const float* __restrict__ aff1,
                                                     const float* __restrict__ aff2,
                                                     const float* __restrict__ W1,
                                                     const float* __restrict__ b1,
                                                     const float* __restrict__ W2,
                                                     const float* __restrict__ b2,
                                                     double* __restrict__ part,
                                                     float* __restrict__ h3max,
                                                     float* __restrict__ h3min) {
    __shared__ __align__(16) float Wl[64 * 128];
    __shared__ float stage[256 * 33 + 8];
    __shared__ float sA1[64], sC1[64], sB1[64], sA2[64], sC2[64], sB2[128];
    __shared__ double r1[8][33], r2[8][33];
    int tid = threadIdx.x;
    for (int i = tid; i < 4096; i += 256) { int o = i >> 6, c = i & 63; Wl[c * 64 + o] = W1[i]; }
    if (tid < 64) {
        sA1[tid] = aff1[tid]; sC1[tid] = aff1[64 + tid]; sB1[tid] = b1[tid];
        sA2[tid] = aff2[tid]; sC2[tid] = aff2[64 + tid];
    }
    __syncthreads();
    int slot = blockIdx.x * 256 + tid;
    int b = slot >> 16; int r = slot & 65535; int s = r >> 5;
    int g = gidx[slot];
    float x[64];
    {
        const float4* qp4 = (const float4*)(Q1 + (((size_t)b << 13) + g) * 64);
        const float4* cp4 = (const float4*)(C1 + ((size_t)(b << 11) + s) * 64);
#pragma unroll
        for (int c4 = 0; c4 < 16; c4++) {
            float4 q = qp4[c4], cc = cp4[c4];
            int c = c4 * 4;
            x[c + 0] = fmaxf(0.f, sA1[c + 0] * (q.x - cc.x) + sC1[c + 0]);
            x[c + 1] = fmaxf(0.f, sA1[c + 1] * (q.y - cc.y) + sC1[c + 1]);
            x[c + 2] = fmaxf(0.f, sA1[c + 2] * (q.z - cc.z) + sC1[c + 2]);
            x[c + 3] = fmaxf(0.f, sA1[c + 3] * (q.w - cc.w) + sC1[c + 3]);
        }
    }
    const float4* Wl4 = (const float4*)Wl;
    float x3[64];
    for (int ch = 0; ch < 2; ch++) {
        float acc[32];
#pragma unroll
        for (int o = 0; o < 32; o++) acc[o] = sB1[ch * 32 + o];
#pragma unroll
        for (int c = 0; c < 64; c++) {
            float xv = x[c];
#pragma unroll
            for (int og = 0; og < 8; og++) {
                float4 w = Wl4[c * 16 + ch * 8 + og];
                acc[og * 4 + 0] += w.x * xv; acc[og * 4 + 1] += w.y * xv;
                acc[og * 4 + 2] += w.z * xv; acc[og * 4 + 3] += w.w * xv;
            }
        }
#pragma unroll
        for (int o = 0; o < 32; o++) {
            int oo = ch * 32 + o;
            x3[oo] = fmaxf(0.f, sA2[oo] * acc[o] + sC2[oo]);
        }
    }
    __syncthreads();  // done with W1 region
    for (int i = tid; i < 8192; i += 256) { int o = i >> 6, c = i & 63; Wl[c * 128 + o] = W2[i]; }
    if (tid < 128) sB2[tid] = b2[tid];
    __syncthreads();
    for (int ch = 0; ch < 4; ch++) {
        float acc[32];
#pragma unroll
        for (int o = 0; o < 32; o++) acc[o] = sB2[ch * 32 + o];
#pragma unroll
        for (int c = 0; c < 64; c++) {
            float xv = x3[c];
#pragma unroll
            for (int og = 0; og < 8; og++) {
                float4 w = Wl4[c * 32 + ch * 8 + og];
                acc[og * 4 + 0] += w.x * xv; acc[og * 4 + 1] += w.y * xv;
                acc[og * 4 + 2] += w.z * xv; acc[og * 4 + 3] += w.w * xv;
            }
        }
#pragma unroll
        for (int o = 0; o < 32; o++) stage[STG(tid, o)] = acc[o];
        __syncthreads();
        int chn = tid & 31, rr = tid >> 5;
        double s1 = 0, s2 = 0;
        float mx = -3.402823466e38f, mn = 3.402823466e38f;
        for (int row = rr * 32; row < rr * 32 + 32; row++) {
            float v = stage[STG(row, chn)];
            s1 += v; s2 += (double)v * (double)v;
            mx = fmaxf(mx, v); mn = fminf(mn, v);
        }
        r1[rr][chn] = s1; r2[rr][chn] = s2;
        int gg = blockIdx.x * 8 + rr;
        int bb_ = gg >> 11, ss_ = gg & 2047;
        h3max[((size_t)bb_ * 128 + ch * 32 + chn) * 2048 + ss_] = mx;
        h3min[((size_t)bb_ * 128 + ch * 32 + chn) * 2048 + ss_] = mn;
        __syncthreads();
        if (tid < 32) {
            double a = 0, bb = 0;
            for (int l = 0; l < 8; l++) { a += r1[l][tid]; bb += r2[l][tid]; }
            part[blockIdx.x * 256 + (ch * 32 + tid) * 2] = a;
            part[blockIdx.x * 256 + (ch * 32 + tid) * 2 + 1] = bb;
        }
        __syncthreads();
    }
}

// ---------------- layer3 fast path: read stored h2 -> x3 -> W2 phase (bit-identical) ----------------
__global__ __launch_bounds__(256) void layer3_fast_kernel(const float* __restrict__ h2in,
                                                          const float* __restrict__ aff2,
                                                          const float* __restrict__ W2,
                                                          const float* __restrict__ b2,
                                                          double* __restrict__ part,
                                                          float* __restrict__ h3max,
                                                          float* __restrict__ h3min) {
    __shared__ __align__(16) float Wl[64 * 128];
    __shared__ float stage[256 * 33 + 8];
    __shared__ float sA2[64], sC2[64], sB2[128];
    __shared__ double r1[8][33], r2[8][33];
    int tid = threadIdx.x;
    for (int i = tid; i < 8192; i += 256) { int o = i >> 6, c = i & 63; Wl[c * 128 + o] = W2[i]; }
    if (tid < 64) { sA2[tid] = aff2[tid]; sC2[tid] = aff2[64 + tid]; }
    if (tid < 128) sB2[tid] = b2[tid];
    __syncthreads();
    int slot = blockIdx.x * 256 + tid;
    float x3[64];
    {
        const float4* h4 = (const float4*)(h2in + (size_t)slot * 64);
#pragma unroll
        for (int c4 = 0; c4 < 16; c4++) {
            float4 h = h4[c4];
            int c = c4 * 4;
            x3[c + 0] = fmaxf(0.f, sA2[c + 0] * h.x + sC2[c + 0]);
            x3[c + 1] = fmaxf(0.f, sA2[c + 1] * h.y + sC2[c + 1]);
            x3[c + 2] = fmaxf(0.f, sA2[c + 2] * h.z + sC2[c + 2]);
            x3[c + 3] = fmaxf(0.f, sA2[c + 3] * h.w + sC2[c + 3]);
        }
    }
    const float4* Wl4 = (const float4*)Wl;
    for (int ch = 0; ch < 4; ch++) {
        float acc[32];
#pragma unroll
        for (int o = 0; o < 32; o++) acc[o] = sB2[ch * 32 + o];
#pragma unroll
        for (int c = 0; c < 64; c++) {
            float xv = x3[c];
#pragma unroll
            for (int og = 0; og < 8; og++) {
                float4 w = Wl4[c * 32 + ch * 8 + og];
                acc[og * 4 + 0] += w.x * xv; acc[og * 4 + 1] += w.y * xv;
                acc[og * 4 + 2] += w.z * xv; acc[og * 4 + 3] += w.w * xv;
            }
        }
#pragma unroll
        for (int o = 0; o < 32; o++) stage[STG(tid, o)] = acc[o];
        __syncthreads();
        int chn = tid & 31, rr = tid >> 5;
        double s1 = 0, s2 = 0;
        float mx = -3.402823466e38f, mn = 3.402823466e38f;
        for (int row = rr * 32; row < rr * 32 + 32; row++) {
            float v = stage[STG(row, chn)];
            s1 += v; s2 += (double)v * (double)v;
            mx = fmaxf(mx, v); mn = fminf(mn, v);
        }
        r1[rr][chn] = s1; r2[rr][chn] = s2;
        int gg = blockIdx.x * 8 + rr;
        int bb_ = gg >> 11, ss_ = gg & 2047;
        h3max[((size_t)bb_ * 128 + ch * 32 + chn) * 2048 + ss_] = mx;
        h3min[((size_t)bb_ * 128 + ch * 32 + chn) * 2048 + ss_] = mn;
        __syncthreads();
        if (tid < 32) {
            double a = 0, bb = 0;
            for (int l = 0; l < 8; l++) { a += r1[l][tid]; bb += r2[l][tid]; }
            part[blockIdx.x * 256 + (ch * 32 + tid) * 2] = a;
            part[blockIdx.x * 256 + (ch * 32 + tid) * 2 + 1] = bb;
        }
        __syncthreads();
    }
}

// ---------------- final: out = relu(a3 * (a3>=0 ? max : min) + c3) ----------------
__global__ void final_kernel(const float* __restrict__ h3max, const float* __restrict__ h3min,
                             const float* __restrict__ aff3, float* __restrict__ out1) {
    int idx = blockIdx.x * 256 + threadIdx.x;  // over B*128*S
    int ch = (idx >> 11) & 127;
    float a = aff3[ch], cv = aff3[128 + ch];
    float v = (a >= 0.f) ? h3max[idx] : h3min[idx];
    out1[idx] = fmaxf(0.f, a * v + cv);
}

extern "C" void kernel_launch(void* const* d_in, const int* in_sizes, int n_in,
                              void* d_out, int out_size, void* d_ws, size_t ws_size,
                              hipStream_t stream) {
    (void)in_sizes; (void)n_in; (void)out_size;
    const float* xyz = (const float*)d_in[0];
    const float* pts = (const float*)d_in[1];
    const float* W0  = (const float*)d_in[2];
    const float* b0  = (const float*)d_in[3];
    const float* g0  = (const float*)d_in[4];
    const float* be0 = (const float*)d_in[5];
    const float* W1  = (const float*)d_in[6];
    const float* b1  = (const float*)d_in[7];
    const float* g1  = (const float*)d_in[8];
    const float* be1 = (const float*)d_in[9];
    const float* W2  = (const float*)d_in[10];
    const float* b2  = (const float*)d_in[11];
    const float* g2  = (const float*)d_in[12];
    const float* be2 = (const float*)d_in[13];

    char* ws = (char*)d_ws;
    double* partA  = (double*)(ws + OFF_PARTA);
    float*  nxyz   = (float*)(ws + OFF_NEWXYZ);
    int*    gidx   = (int*)(ws + OFF_GIDX);
    float*  Q1     = (float*)(ws + OFF_Q1);
    float*  C1b    = (float*)(ws + OFF_C1);
    double* part   = (double*)(ws + OFF_PART);
    float*  aff1   = (float*)(ws + OFF_AFF1);
    float*  aff2   = (float*)(ws + OFF_AFF2);
    float*  aff3   = (float*)(ws + OFF_AFF3);
    float*  h3mx   = (float*)(ws + OFF_H3MAX);
    float*  h3mn   = (float*)(ws + OFF_H3MIN);
    float*  out0   = (float*)d_out;
    float*  out1   = out0 + B_ * 3 * S_;

    bool useH2 = ws_size >= WS_NEED_H2;
    float* h2buf = useH2 ? (float*)(ws + OFF_H2) : (float*)0;

    fps_kernel<<<16 + 16384, 512, 0, stream>>>(xyz, pts, W0, b0, Q1, nxyz, out0);
    ball_kernel<<<B_ * S_, 64, 0, stream>>>(xyz, nxyz, gidx);
    c1_kernel<<<(B_ * S_) / 4, 256, 0, stream>>>(nxyz, W0, C1b);
    stats1_kernel<<<1024, 256, 0, stream>>>(Q1, C1b, gidx, part);
    stats_reduceA_kernel<<<64, 256, 0, stream>>>(part, 1024, partA);
    stats_reduce_kernel<<<1, 256, 0, stream>>>(partA, 64, 64, g0, be0, aff1);
    layer2_stats_kernel<<<4096, 256, 0, stream>>>(Q1, C1b, gidx, aff1, W1, b1, part, h2buf);
    stats_reduceA_kernel<<<64, 256, 0, stream>>>(part, 4096, partA);
    stats_reduce_kernel<<<1, 256, 0, stream>>>(partA, 64, 64, g1, be1, aff2);
    if (useH2) {
        layer3_fast_kernel<<<4096, 256, 0, stream>>>(h2buf, aff2, W2, b2, part, h3mx, h3mn);
    } else {
        layer3_kernel<<<4096, 256, 0, stream>>>(Q1, C1b, gidx, aff1, aff2, W1, b1, W2, b2,
                                                part, h3mx, h3mn);
    }
    stats_reduceA_kernel<<<64, 256, 0, stream>>>(part, 4096, partA);
    stats_reduce_kernel<<<1, 512, 0, stream>>>(partA, 64, 128, g2, be2, aff3);
    final_kernel<<<(B_ * 128 * S_) / 256, 256, 0, stream>>>(h3mx, h3mn, aff3, out1);
}

// Round 18
// 3512.865 us; speedup vs baseline: 1.0223x; 1.0223x over previous
//
#include <hip/hip_runtime.h>

#define B_ 16
#define N_ 8192
#define S_ 2048
#define K_ 32
#define EPSBN 1e-5
#define CAP 1024

// workspace offsets (bytes)
#define OFF_PARTA    0ul            // 64*256*8 = 131072 (dead zone)
#define OFF_NEWXYZ   131072ul
#define OFF_GIDX     524288ul
#define OFF_Q1       4718592ul
#define OFF_C1       38273024ul
#define OFF_PART     46661632ul
#define OFF_AFF1     55050240ul
#define OFF_AFF2     55051264ul
#define OFF_AFF3     55052288ul
#define OFF_H3MAX    55053312ul
#define OFF_H3MIN    71830528ul

#define STG(row, c) ((row)*33 + ((row)>>5) + (c))

// ---- DPP helpers: wave64 u64 reduce to lane 63 (row_shr 1/2/4/8 + row_bcast15/31) ----
template<int CTRL, int RM>
__device__ __forceinline__ unsigned long long dppmove(unsigned long long x) {
    unsigned int lo = (unsigned int)x, hi = (unsigned int)(x >> 32);
    unsigned int lo2 = (unsigned int)__builtin_amdgcn_update_dpp((int)lo, (int)lo, CTRL, RM, 0xf, false);
    unsigned int hi2 = (unsigned int)__builtin_amdgcn_update_dpp((int)hi, (int)hi, CTRL, RM, 0xf, false);
    return ((unsigned long long)hi2 << 32) | lo2;
}
__device__ __forceinline__ unsigned long long wave_max_u64(unsigned long long x) {
    unsigned long long t;
    t = dppmove<0x111, 0xf>(x); x = (t > x) ? t : x;  // row_shr:1
    t = dppmove<0x112, 0xf>(x); x = (t > x) ? t : x;  // row_shr:2
    t = dppmove<0x114, 0xf>(x); x = (t > x) ? t : x;  // row_shr:4
    t = dppmove<0x118, 0xf>(x); x = (t > x) ? t : x;  // row_shr:8
    t = dppmove<0x142, 0xa>(x); x = (t > x) ? t : x;  // row_bcast15 -> rows 1,3
    t = dppmove<0x143, 0xc>(x); x = (t > x) ? t : x;  // row_bcast31 -> rows 2,3
    return x;  // lane 63 holds the max
}
__device__ __forceinline__ unsigned long long wave_min_u64(unsigned long long x) {
    unsigned long long t;
    t = dppmove<0x111, 0xf>(x); x = (t < x) ? t : x;
    t = dppmove<0x112, 0xf>(x); x = (t < x) ? t : x;
    t = dppmove<0x114, 0xf>(x); x = (t < x) ? t : x;
    t = dppmove<0x118, 0xf>(x); x = (t < x) ? t : x;
    t = dppmove<0x142, 0xa>(x); x = (t < x) ? t : x;
    t = dppmove<0x143, 0xc>(x); x = (t < x) ? t : x;
    return x;  // lane 63 holds the min
}

// ---------------- FPS (blocks 0..15; 1 working wave/SIMD) + fused Q1 (blocks 16+) ----------------
__global__ __launch_bounds__(512) void fps_kernel(const float* __restrict__ xyz,
                                                  const float* __restrict__ pts,
                                                  const float* __restrict__ W0,
                                                  const float* __restrict__ b0,
                                                  float* __restrict__ Q1,
                                                  float* __restrict__ nxyz,
                                                  float* __restrict__ out0) {
    __shared__ float xs[N_], ys[N_], zs[N_];
    __shared__ int farHist[S_];
    __shared__ unsigned long long kq[2][4];
    int tid = threadIdx.x;
    if (blockIdx.x >= 16) {
        // ---- Q1 = W0 @ [xyz;points] + b0 (independent of FPS; fills idle CUs) ----
        int o = tid & 63, jj = tid >> 6;           // 8 points per block
        int blk = blockIdx.x - 16;                  // 0..16383
        int b = blk >> 10;
        int j = ((blk & 1023) << 3) + jj;
        const float* xb = xyz + (size_t)b * 3 * N_;
        const float* pb = pts + (size_t)b * 64 * N_;
        float acc = b0[o];
#pragma unroll
        for (int c = 0; c < 3; c++) acc += W0[o * 67 + c] * xb[c * N_ + j];
#pragma unroll 8
        for (int c = 0; c < 64; c++) acc += W0[o * 67 + 3 + c] * pb[c * N_ + j];
        Q1[(((size_t)b << 13) + j) * 64 + o] = acc;
        return;
    }
    int b = blockIdx.x;
    const float* xb = xyz + (size_t)b * 3 * N_;
    for (int i = tid; i < N_; i += 512) {
        xs[i] = xb[i]; ys[i] = xb[N_ + i]; zs[i] = xb[2 * N_ + i];
    }
    __syncthreads();
    // only threads < 256 run the FPS core: 1 working wave per SIMD (uninterleaved chain)
    float px[32], py[32], pz[32], d8[32];
    if (tid < 256) {
#pragma unroll
        for (int k = 0; k < 32; k++) {
            int i = tid + k * 256;
            px[k] = xs[i]; py[k] = ys[i]; pz[k] = zs[i];
            d8[k] = 1e10f;
        }
    }
    int far = 0;
    int w = tid >> 6;
    for (int t = 0; t < S_; t++) {
        if (tid < 256) {
            if (tid == 0) farHist[t] = far;
            float cx = xs[far], cy = ys[far], cz = zs[far];
            float bv = -1.f; int bk = 0;
#pragma unroll
            for (int k = 0; k < 32; k++) {
                float dx = px[k] - cx, dy = py[k] - cy, dz = pz[k] - cz;
                float d = dx * dx + dy * dy + dz * dz;
                float dd = fminf(d8[k], d); d8[k] = dd;
                if (dd > bv) { bv = dd; bk = k; }   // strict >: smallest k (= smallest idx) wins ties
            }
            int bi = tid + bk * 256;
            unsigned long long kk = (((unsigned long long)__float_as_uint(bv)) << 32)
                                  | (unsigned)(8191 - bi);
            kk = wave_max_u64(kk);
            if ((tid & 63) == 63) kq[t & 1][w] = kk;
        }
        __syncthreads();
        if (tid < 256) {
            int buf = t & 1;
            unsigned long long fk = kq[buf][0];
#pragma unroll
            for (int q = 1; q < 4; q++) { unsigned long long o = kq[buf][q]; fk = (o > fk) ? o : fk; }
            far = 8191 - (int)(fk & 0xffffffffull);
        }
    }
    __syncthreads();
    // fused gather: nxyz + out0
    for (int s = tid; s < S_; s += 512) {
        int idx = farHist[s];
        float x = xs[idx], y = ys[idx], z = zs[idx];
        int g = b * S_ + s;
        nxyz[g * 3 + 0] = x; nxyz[g * 3 + 1] = y; nxyz[g * 3 + 2] = z;
        out0[(b * 3 + 0) * S_ + s] = x;
        out0[(b * 3 + 1) * S_ + s] = y;
        out0[(b * 3 + 2) * S_ + s] = z;
    }
}

// ---------------- ball query: 64-thr blocks; FMA-chain distance; atomic compaction; DPP selection ----------------
__global__ __launch_bounds__(64) void ball_kernel(const float* __restrict__ xyz,
                                                  const float* __restrict__ nxyz,
                                                  int* __restrict__ gidx) {
    __shared__ unsigned long long keys[CAP];
    __shared__ int cnt;
    int bs = blockIdx.x; int b = bs >> 11; int tid = threadIdx.x;
    const float* xb = xyz + (size_t)b * 3 * N_;
    float cx = nxyz[bs * 3 + 0], cy = nxyz[bs * 3 + 1], cz = nxyz[bs * 3 + 2];
    float csq = __fadd_rn(__fadd_rn(__fmul_rn(cx, cx), __fmul_rn(cy, cy)), __fmul_rn(cz, cz));
    const float R2F = (float)(0.45 * 0.45);
    if (tid == 0) cnt = 0;
    __syncthreads();
    for (int j = tid; j < N_; j += 64) {
        float qx = xb[j], qy = xb[N_ + j], qz = xb[2 * N_ + j];
        float psq = __fadd_rn(__fadd_rn(__fmul_rn(qx, qx), __fmul_rn(qy, qy)), __fmul_rn(qz, qz));
        float t = __fmul_rn(cx, qx);
        t = __fmaf_rn(cy, qy, t);
        t = __fmaf_rn(cz, qz, t);
        float d2 = __fsub_rn(__fadd_rn(csq, psq), __fadd_rn(t, t));  // 2*t exact
        float dist = __fsqrt_rn(fmaxf(d2, 0.0f));
        if (dist < R2F) {
            int p = atomicAdd(&cnt, 1);
            if (p < CAP) keys[p] = (((unsigned long long)__float_as_uint(dist)) << 32) | (unsigned)j;
        }
    }
    __syncthreads();
    int nc = cnt; if (nc > CAP) nc = CAP;
    for (int k = 0; k < K_; k++) {
        unsigned long long bk = ~0ull;
        for (int i = tid; i < nc; i += 64) {
            unsigned long long kv = keys[i];
            bk = (kv < bk) ? kv : bk;
        }
        bk = wave_min_u64(bk);
        unsigned int lo = (unsigned int)__builtin_amdgcn_readlane((int)(unsigned int)bk, 63);
        unsigned int hi = (unsigned int)__builtin_amdgcn_readlane((int)(unsigned int)(bk >> 32), 63);
        unsigned long long mk = ((unsigned long long)hi << 32) | lo;
        int j = 0;
        if (mk != ~0ull) {
            j = (int)(mk & 0xffffffffull);
            for (int i = tid; i < nc; i += 64)
                if (keys[i] == mk) keys[i] = ~0ull;
        }
        if (tid == 0) gidx[bs * K_ + k] = j;
    }
}

// ---------------- C1 = W0[:, :3] @ centroid ----------------
__global__ __launch_bounds__(256) void c1_kernel(const float* __restrict__ nxyz,
                                                 const float* __restrict__ W0,
                                                 float* __restrict__ C1) {
    int tid = threadIdx.x; int o = tid & 63, ss = tid >> 6;
    int gs = blockIdx.x * 4 + ss;  // over B*S
    float acc = 0.f;
#pragma unroll
    for (int c = 0; c < 3; c++) acc += W0[o * 67 + c] * nxyz[gs * 3 + c];
    C1[(size_t)gs * 64 + o] = acc;
}

// ---------------- stats of h1 = Q1[g] - C1[s] ----------------
__global__ __launch_bounds__(256) void stats1_kernel(const float* __restrict__ Q1,
                                                     const float* __restrict__ C1,
                                                     const int* __restrict__ gidx,
                                                     double* __restrict__ part) {
    __shared__ double ds1[4][64], ds2[4][64];
    int tid = threadIdx.x; int o = tid & 63, ll = tid >> 6;
    double s1 = 0, s2 = 0;
    for (int it = 0; it < 256; it++) {
        int slot = it * 4096 + blockIdx.x * 4 + ll;
        int b = slot >> 16; int r = slot & 65535; int s = r >> 5;
        int g = gidx[slot];
        float q = Q1[(((size_t)b << 13) + g) * 64 + o];
        float c = C1[((size_t)(b << 11) + s) * 64 + o];
        float h = q - c;
        s1 += h; s2 += (double)h * (double)h;
    }
    ds1[ll][o] = s1; ds2[ll][o] = s2;
    __syncthreads();
    if (tid < 64) {
        double a = 0, bb = 0;
        for (int l = 0; l < 4; l++) { a += ds1[l][tid]; bb += ds2[l][tid]; }
        part[blockIdx.x * 256 + tid * 2] = a;
        part[blockIdx.x * 256 + tid * 2 + 1] = bb;
    }
}

// ---------------- stage-A reduce: 64 blocks, each sums nblocks/64 part rows ----------------
__global__ void stats_reduceA_kernel(const double* __restrict__ part, int nblocks,
                                     double* __restrict__ partA) {
    int per = nblocks >> 6;
    int a = blockIdx.x;
    int c = threadIdx.x;  // 256 threads, one column each
    double s = 0;
    for (int k = 0; k < per; k++)
        s += part[((size_t)(a * per + k)) * 256 + c];
    partA[(size_t)a * 256 + c] = s;
}

// ---------------- stage-B reduce -> affine (a, c); launch with 4*C threads ----------------
__global__ void stats_reduce_kernel(const double* __restrict__ part, int nblocks, int C,
                                    const float* __restrict__ gamma, const float* __restrict__ beta,
                                    float* __restrict__ aff) {
    __shared__ double s1s[512], s2s[512];
    int tid = threadIdx.x;
    int q = tid / C; int o = tid - q * C;
    double s1 = 0, s2 = 0;
    for (int i = q; i < nblocks; i += 4) {
        s1 += part[(size_t)i * 256 + o * 2];
        s2 += part[(size_t)i * 256 + o * 2 + 1];
    }
    s1s[tid] = s1; s2s[tid] = s2;
    __syncthreads();
    if (tid < C) {
        double a1 = s1s[tid] + s1s[tid + C] + s1s[tid + 2 * C] + s1s[tid + 3 * C];
        double a2 = s2s[tid] + s2s[tid + C] + s2s[tid + 2 * C] + s2s[tid + 3 * C];
        const double cnt = 1048576.0;
        double mean = a1 / cnt;
        double var = a2 / cnt - mean * mean; if (var < 0) var = 0;
        double a = (double)gamma[tid] / sqrt(var + EPSBN);
        double c = (double)beta[tid] - a * mean;
        aff[tid] = (float)a; aff[C + tid] = (float)c;
    }
}

// ---------------- layer2 (h2 = W1 @ relu(bn1(h1))) + stats of h2 ----------------
__global__ __launch_bounds__(256) void layer2_stats_kernel(const float* __restrict__ Q1,
                                                           const float* __restrict__ C1,
                                                           const int* __restrict__ gidx,
                                                           const float* __restrict__ aff1,
                                                           const float* __restrict__ W1,
                                                           const float* __restrict__ b1,
                                                           double* __restrict__ part) {
    __shared__ __align__(16) float Wl[64 * 64];
    __shared__ float stage[256 * 33 + 8];
    __shared__ float sA[64], sC[64], sB[64];
    __shared__ double r1[8][33], r2[8][33];
    int tid = threadIdx.x;
    for (int i = tid; i < 4096; i += 256) { int o = i >> 6, c = i & 63; Wl[c * 64 + o] = W1[i]; }
    if (tid < 64) { sA[tid] = aff1[tid]; sC[tid] = aff1[64 + tid]; sB[tid] = b1[tid]; }
    __syncthreads();
    int slot = blockIdx.x * 256 + tid;
    int b = slot >> 16; int r = slot & 65535; int s = r >> 5;
    int g = gidx[slot];
    float x[64];
    {
        const float4* qp4 = (const float4*)(Q1 + (((size_t)b << 13) + g) * 64);
        const float4* cp4 = (const float4*)(C1 + ((size_t)(b << 11) + s) * 64);
#pragma unroll
        for (int c4 = 0; c4 < 16; c4++) {
            float4 q = qp4[c4], cc = cp4[c4];
            int c = c4 * 4;
            x[c + 0] = fmaxf(0.f, sA[c + 0] * (q.x - cc.x) + sC[c + 0]);
            x[c + 1] = fmaxf(0.f, sA[c + 1] * (q.y - cc.y) + sC[c + 1]);
            x[c + 2] = fmaxf(0.f, sA[c + 2] * (q.z - cc.z) + sC[c + 2]);
            x[c + 3] = fmaxf(0.f, sA[c + 3] * (q.w - cc.w) + sC[c + 3]);
        }
    }
    const float4* Wl4 = (const float4*)Wl;
    for (int ch = 0; ch < 2; ch++) {
        float acc[32];
#pragma unroll
        for (int o = 0; o < 32; o++) acc[o] = sB[ch * 32 + o];
#pragma unroll
        for (int c = 0; c < 64; c++) {
            float xv = x[c];
#pragma unroll
            for (int og = 0; og < 8; og++) {
                float4 w = Wl4[c * 16 + ch * 8 + og];
                acc[og * 4 + 0] += w.x * xv; acc[og * 4 + 1] += w.y * xv;
                acc[og * 4 + 2] += w.z * xv; acc[og * 4 + 3] += w.w * xv;
            }
        }
#pragma unroll
        for (int o = 0; o < 32; o++) stage[STG(tid, o)] = acc[o];
        __syncthreads();
        int chn = tid & 31, rr = tid >> 5;
        double s1 = 0, s2 = 0;
        for (int row = rr * 32; row < rr * 32 + 32; row++) {
            float v = stage[STG(row, chn)];
            s1 += v; s2 += (double)v * (double)v;
        }
        r1[rr][chn] = s1; r2[rr][chn] = s2;
        __syncthreads();
        if (tid < 32) {
            double a = 0, bb = 0;
            for (int l = 0; l < 8; l++) { a += r1[l][tid]; bb += r2[l][tid]; }
            part[blockIdx.x * 256 + (ch * 32 + tid) * 2] = a;
            part[blockIdx.x * 256 + (ch * 32 + tid) * 2 + 1] = bb;
        }
        __syncthreads();
    }
}

// ---------------- layer3: recompute h2 -> x3 -> h3; stats of h3 + per-group min/max ----------------
// h3 layout: GROUP-MAJOR h3[gg*128 + ch*32+chn]  (coalesced wave stores: 256B contiguous)
__global__ __launch_bounds__(256) void layer3_kernel(const float* __restrict__ Q1,
                                                     const float* __restrict__ C1,
                                                     const int* __restrict__ gidx,
                                                     const float* __restrict__ aff1,
                                                     const float* __restrict__ aff2,
                                                     const float* __restrict__ W1,
                                                     const float* __restrict__ b1,
                                                     const float* __restrict__ W2,
                                                     const float* __restrict__ b2,
                                                     double* __restrict__ part,
                                                     float* __restrict__ h3max,
                                                     float* __restrict__ h3min) {
    __shared__ __align__(16) float Wl[64 * 128];
    __shared__ float stage[256 * 33 + 8];
    __shared__ float sA1[64], sC1[64], sB1[64], sA2[64], sC2[64], sB2[128];
    __shared__ double r1[8][33], r2[8][33];
    int tid = threadIdx.x;
    for (int i = tid; i < 4096; i += 256) { int o = i >> 6, c = i & 63; Wl[c * 64 + o] = W1[i]; }
    if (tid < 64) {
        sA1[tid] = aff1[tid]; sC1[tid] = aff1[64 + tid]; sB1[tid] = b1[tid];
        sA2[tid] = aff2[tid]; sC2[tid] = aff2[64 + tid];
    }
    __syncthreads();
    int slot = blockIdx.x * 256 + tid;
    int b = slot >> 16; int r = slot & 65535; int s = r >> 5;
    int g = gidx[slot];
    float x[64];
    {
        const float4* qp4 = (const float4*)(Q1 + (((size_t)b << 13) + g) * 64);
        const float4* cp4 = (const float4*)(C1 + ((size_t)(b << 11) + s) * 64);
#pragma unroll
        for (int c4 = 0; c4 < 16; c4++) {
            float4 q = qp4[c4], cc = cp4[c4];
            int c = c4 * 4;
            x[c + 0] = fmaxf(0.f, sA1[c + 0] * (q.x - cc.x) + sC1[c + 0]);
            x[c + 1] = fmaxf(0.f, sA1[c + 1] * (q.y - cc.y) + sC1[c + 1]);
            x[c + 2] = fmaxf(0.f, sA1[c + 2] * (q.z - cc.z) + sC1[c + 2]);
            x[c + 3] = fmaxf(0.f, sA1[c + 3] * (q.w - cc.w) + sC1[c + 3]);
        }
    }
    const float4* Wl4 = (const float4*)Wl;
    float x3[64];
    for (int ch = 0; ch < 2; ch++) {
        float acc[32];
#pragma unroll
        for (int o = 0; o < 32; o++) acc[o] = sB1[ch * 32 + o];
#pragma unroll
        for (int c = 0; c < 64; c++) {
            float xv = x[c];
#pragma unroll
            for (int og = 0; og < 8; og++) {
                float4 w = Wl4[c * 16 + ch * 8 + og];
                acc[og * 4 + 0] += w.x * xv; acc[og * 4 + 1] += w.y * xv;
                acc[og * 4 + 2] += w.z * xv; acc[og * 4 + 3] += w.w * xv;
            }
        }
#pragma unroll
        for (int o = 0; o < 32; o++) {
            int oo = ch * 32 + o;
            x3[oo] = fmaxf(0.f, sA2[oo] * acc[o] + sC2[oo]);
        }
    }
    __syncthreads();  // done with W1 region
    for (int i = tid; i < 8192; i += 256) { int o = i >> 6, c = i & 63; Wl[c * 128 + o] = W2[i]; }
    if (tid < 128) sB2[tid] = b2[tid];
    __syncthreads();
    for (int ch = 0; ch < 4; ch++) {
        float acc[32];
#pragma unroll
        for (int o = 0; o < 32; o++) acc[o] = sB2[ch * 32 + o];
#pragma unroll
        for (int c = 0; c < 64; c++) {
            float xv = x3[c];
#pragma unroll
            for (int og = 0; og < 8; og++) {
                float4 w = Wl4[c * 32 + ch * 8 + og];
                acc[og * 4 + 0] += w.x * xv; acc[og * 4 + 1] += w.y * xv;
                acc[og * 4 + 2] += w.z * xv; acc[og * 4 + 3] += w.w * xv;
            }
        }
#pragma unroll
        for (int o = 0; o < 32; o++) stage[STG(tid, o)] = acc[o];
        __syncthreads();
        int chn = tid & 31, rr = tid >> 5;
        double s1 = 0, s2 = 0;
        float mx = -3.402823466e38f, mn = 3.402823466e38f;
        for (int row = rr * 32; row < rr * 32 + 32; row++) {
            float v = stage[STG(row, chn)];
            s1 += v; s2 += (double)v * (double)v;
            mx = fmaxf(mx, v); mn = fminf(mn, v);
        }
        r1[rr][chn] = s1; r2[rr][chn] = s2;
        int gg = blockIdx.x * 8 + rr;
        h3max[(size_t)gg * 128 + ch * 32 + chn] = mx;   // coalesced group-major store
        h3min[(size_t)gg * 128 + ch * 32 + chn] = mn;
        __syncthreads();
        if (tid < 32) {
            double a = 0, bb = 0;
            for (int l = 0; l < 8; l++) { a += r1[l][tid]; bb += r2[l][tid]; }
            part[blockIdx.x * 256 + (ch * 32 + tid) * 2] = a;
            part[blockIdx.x * 256 + (ch * 32 + tid) * 2 + 1] = bb;
        }
        __syncthreads();
    }
}

// ---------------- final v2: coalesced read of group-major h3; LDS transpose; 64B-run writes ----------------
__global__ __launch_bounds__(256) void final_kernel(const float* __restrict__ h3max,
                                                    const float* __restrict__ h3min,
                                                    const float* __restrict__ aff3,
                                                    float* __restrict__ out1) {
    __shared__ float tmx[128][17], tmn[128][17];
    __shared__ float sA3[128], sC3[128];
    int tid = threadIdx.x;
    int gg0 = blockIdx.x * 16;        // 16 groups per block, all in same batch b
    if (tid < 128) { sA3[tid] = aff3[tid]; sC3[tid] = aff3[128 + tid]; }
#pragma unroll
    for (int e = 0; e < 8; e++) {
        int t = e * 256 + tid;         // 0..2047
        int gl = t >> 7, c = t & 127;
        tmx[c][gl] = h3max[(size_t)gg0 * 128 + t];   // consecutive t -> coalesced
        tmn[c][gl] = h3min[(size_t)gg0 * 128 + t];
    }
    __syncthreads();
    int b = gg0 >> 11;
    int ss0 = gg0 & 2047;
#pragma unroll
    for (int e = 0; e < 8; e++) {
        int t = e * 256 + tid;
        int c = t >> 4, gl = t & 15;
        float a = sA3[c], cv = sC3[c];
        float v = (a >= 0.f) ? tmx[c][gl] : tmn[c][gl];
        out1[((size_t)b * 128 + c) * 2048 + ss0 + gl] = fmaxf(0.f, a * v + cv);
    }
}

extern "C" void kernel_launch(void* const* d_in, const int* in_sizes, int n_in,
                              void* d_out, int out_size, void* d_ws, size_t ws_size,
                              hipStream_t stream) {
    (void)in_sizes; (void)n_in; (void)out_size; (void)ws_size;
    const float* xyz = (const float*)d_in[0];
    const float* pts = (const float*)d_in[1];
    const float* W0  = (const float*)d_in[2];
    const float* b0  = (const float*)d_in[3];
    const float* g0  = (const float*)d_in[4];
    const float* be0 = (const float*)d_in[5];
    const float* W1  = (const float*)d_in[6];
    const float* b1  = (const float*)d_in[7];
    const float* g1  = (const float*)d_in[8];
    const float* be1 = (const float*)d_in[9];
    const float* W2  = (const float*)d_in[10];
    const float* b2  = (const float*)d_in[11];
    const float* g2  = (const float*)d_in[12];
    const float* be2 = (const float*)d_in[13];

    char* ws = (char*)d_ws;
    double* partA  = (double*)(ws + OFF_PARTA);
    float*  nxyz   = (float*)(ws + OFF_NEWXYZ);
    int*    gidx   = (int*)(ws + OFF_GIDX);
    float*  Q1     = (float*)(ws + OFF_Q1);
    float*  C1b    = (float*)(ws + OFF_C1);
    double* part   = (double*)(ws + OFF_PART);
    float*  aff1   = (float*)(ws + OFF_AFF1);
    float*  aff2   = (float*)(ws + OFF_AFF2);
    float*  aff3   = (float*)(ws + OFF_AFF3);
    float*  h3mx   = (float*)(ws + OFF_H3MAX);
    float*  h3mn   = (float*)(ws + OFF_H3MIN);
    float*  out0   = (float*)d_out;
    float*  out1   = out0 + B_ * 3 * S_;

    fps_kernel<<<16 + 16384, 512, 0, stream>>>(xyz, pts, W0, b0, Q1, nxyz, out0);
    ball_kernel<<<B_ * S_, 64, 0, stream>>>(xyz, nxyz, gidx);
    c1_kernel<<<(B_ * S_) / 4, 256, 0, stream>>>(nxyz, W0, C1b);
    stats1_kernel<<<1024, 256, 0, stream>>>(Q1, C1b, gidx, part);
    stats_reduceA_kernel<<<64, 256, 0, stream>>>(part, 1024, partA);
    stats_reduce_kernel<<<1, 256, 0, stream>>>(partA, 64, 64, g0, be0, aff1);
    layer2_stats_kernel<<<4096, 256, 0, stream>>>(Q1, C1b, gidx, aff1, W1, b1, part);
    stats_reduceA_kernel<<<64, 256, 0, stream>>>(part, 4096, partA);
    stats_reduce_kernel<<<1, 256, 0, stream>>>(partA, 64, 64, g1, be1, aff2);
    layer3_kernel<<<4096, 256, 0, stream>>>(Q1, C1b, gidx, aff1, aff2, W1, b1, W2, b2,
                                            part, h3mx, h3mn);
    stats_reduceA_kernel<<<64, 256, 0, stream>>>(part, 4096, partA);
    stats_reduce_kernel<<<1, 512, 0, stream>>>(partA, 64, 128, g2, be2, aff3);
    final_kernel<<<(B_ * S_) / 16, 256, 0, stream>>>(h3mx, h3mn, aff3, out1);
}

// Round 19
// 3208.611 us; speedup vs baseline: 1.1192x; 1.0948x over previous
//
#include <hip/hip_runtime.h>
#include <hip/hip_fp16.h>

#define B_ 16
#define N_ 8192
#define S_ 2048
#define K_ 32
#define EPSBN 1e-5
#define CAP 1024

// workspace offsets (bytes)
#define OFF_PARTA    0ul            // 64*256*8 = 131072 (dead zone)
#define OFF_NEWXYZ   131072ul
#define OFF_GIDX     524288ul
#define OFF_Q1       4718592ul
#define OFF_C1       38273024ul
#define OFF_PART     46661632ul
#define OFF_AFF1     55050240ul
#define OFF_AFF2     55051264ul
#define OFF_AFF3     55052288ul
#define OFF_H3MAX    55053312ul
#define OFF_H3MIN    71830528ul
#define OFF_H2       88607744ul     // 1M*64*2 = 134217728 (f16)
#define WS_NEED_H2   (OFF_H2 + 134217728ul)

#define STG(row, c) ((row)*33 + ((row)>>5) + (c))

// ---- DPP helpers: wave64 u64 reduce to lane 63 (row_shr 1/2/4/8 + row_bcast15/31) ----
template<int CTRL, int RM>
__device__ __forceinline__ unsigned long long dppmove(unsigned long long x) {
    unsigned int lo = (unsigned int)x, hi = (unsigned int)(x >> 32);
    unsigned int lo2 = (unsigned int)__builtin_amdgcn_update_dpp((int)lo, (int)lo, CTRL, RM, 0xf, false);
    unsigned int hi2 = (unsigned int)__builtin_amdgcn_update_dpp((int)hi, (int)hi, CTRL, RM, 0xf, false);
    return ((unsigned long long)hi2 << 32) | lo2;
}
__device__ __forceinline__ unsigned long long wave_max_u64(unsigned long long x) {
    unsigned long long t;
    t = dppmove<0x111, 0xf>(x); x = (t > x) ? t : x;  // row_shr:1
    t = dppmove<0x112, 0xf>(x); x = (t > x) ? t : x;  // row_shr:2
    t = dppmove<0x114, 0xf>(x); x = (t > x) ? t : x;  // row_shr:4
    t = dppmove<0x118, 0xf>(x); x = (t > x) ? t : x;  // row_shr:8
    t = dppmove<0x142, 0xa>(x); x = (t > x) ? t : x;  // row_bcast15 -> rows 1,3
    t = dppmove<0x143, 0xc>(x); x = (t > x) ? t : x;  // row_bcast31 -> rows 2,3
    return x;  // lane 63 holds the max
}
__device__ __forceinline__ unsigned long long wave_min_u64(unsigned long long x) {
    unsigned long long t;
    t = dppmove<0x111, 0xf>(x); x = (t < x) ? t : x;
    t = dppmove<0x112, 0xf>(x); x = (t < x) ? t : x;
    t = dppmove<0x114, 0xf>(x); x = (t < x) ? t : x;
    t = dppmove<0x118, 0xf>(x); x = (t < x) ? t : x;
    t = dppmove<0x142, 0xa>(x); x = (t < x) ? t : x;
    t = dppmove<0x143, 0xc>(x); x = (t < x) ? t : x;
    return x;  // lane 63 holds the min
}

// ---------------- FPS (blocks 0..15; 1 working wave/SIMD) + fused Q1 (blocks 16+) ----------------
__global__ __launch_bounds__(512) void fps_kernel(const float* __restrict__ xyz,
                                                  const float* __restrict__ pts,
                                                  const float* __restrict__ W0,
                                                  const float* __restrict__ b0,
                                                  float* __restrict__ Q1,
                                                  float* __restrict__ nxyz,
                                                  float* __restrict__ out0) {
    __shared__ float xs[N_], ys[N_], zs[N_];
    __shared__ int farHist[S_];
    __shared__ unsigned long long kq[2][4];
    int tid = threadIdx.x;
    if (blockIdx.x >= 16) {
        // ---- Q1 = W0 @ [xyz;points] + b0 (independent of FPS; fills idle CUs) ----
        int o = tid & 63, jj = tid >> 6;           // 8 points per block
        int blk = blockIdx.x - 16;                  // 0..16383
        int b = blk >> 10;
        int j = ((blk & 1023) << 3) + jj;
        const float* xb = xyz + (size_t)b * 3 * N_;
        const float* pb = pts + (size_t)b * 64 * N_;
        float acc = b0[o];
#pragma unroll
        for (int c = 0; c < 3; c++) acc += W0[o * 67 + c] * xb[c * N_ + j];
#pragma unroll 8
        for (int c = 0; c < 64; c++) acc += W0[o * 67 + 3 + c] * pb[c * N_ + j];
        Q1[(((size_t)b << 13) + j) * 64 + o] = acc;
        return;
    }
    int b = blockIdx.x;
    const float* xb = xyz + (size_t)b * 3 * N_;
    for (int i = tid; i < N_; i += 512) {
        xs[i] = xb[i]; ys[i] = xb[N_ + i]; zs[i] = xb[2 * N_ + i];
    }
    __syncthreads();
    // only threads < 256 run the FPS core: 1 working wave per SIMD (uninterleaved chain)
    float px[32], py[32], pz[32], d8[32];
    if (tid < 256) {
#pragma unroll
        for (int k = 0; k < 32; k++) {
            int i = tid + k * 256;
            px[k] = xs[i]; py[k] = ys[i]; pz[k] = zs[i];
            d8[k] = 1e10f;
        }
    }
    int far = 0;
    int w = tid >> 6;
    for (int t = 0; t < S_; t++) {
        if (tid < 256) {
            if (tid == 0) farHist[t] = far;
            float cx = xs[far], cy = ys[far], cz = zs[far];
            float bv = -1.f; int bk = 0;
#pragma unroll
            for (int k = 0; k < 32; k++) {
                float dx = px[k] - cx, dy = py[k] - cy, dz = pz[k] - cz;
                float d = dx * dx + dy * dy + dz * dz;
                float dd = fminf(d8[k], d); d8[k] = dd;
                if (dd > bv) { bv = dd; bk = k; }   // strict >: smallest k (= smallest idx) wins ties
            }
            int bi = tid + bk * 256;
            unsigned long long kk = (((unsigned long long)__float_as_uint(bv)) << 32)
                                  | (unsigned)(8191 - bi);
            kk = wave_max_u64(kk);
            if ((tid & 63) == 63) kq[t & 1][w] = kk;
        }
        __syncthreads();
        if (tid < 256) {
            int buf = t & 1;
            unsigned long long fk = kq[buf][0];
#pragma unroll
            for (int q = 1; q < 4; q++) { unsigned long long o = kq[buf][q]; fk = (o > fk) ? o : fk; }
            far = 8191 - (int)(fk & 0xffffffffull);
        }
    }
    __syncthreads();
    // fused gather: nxyz + out0
    for (int s = tid; s < S_; s += 512) {
        int idx = farHist[s];
        float x = xs[idx], y = ys[idx], z = zs[idx];
        int g = b * S_ + s;
        nxyz[g * 3 + 0] = x; nxyz[g * 3 + 1] = y; nxyz[g * 3 + 2] = z;
        out0[(b * 3 + 0) * S_ + s] = x;
        out0[(b * 3 + 1) * S_ + s] = y;
        out0[(b * 3 + 2) * S_ + s] = z;
    }
}

// ---------------- ball query: 64-thr blocks; FMA-chain distance; atomic compaction; DPP selection ----------------
__global__ __launch_bounds__(64) void ball_kernel(const float* __restrict__ xyz,
                                                  const float* __restrict__ nxyz,
                                                  int* __restrict__ gidx) {
    __shared__ unsigned long long keys[CAP];
    __shared__ int cnt;
    int bs = blockIdx.x; int b = bs >> 11; int tid = threadIdx.x;
    const float* xb = xyz + (size_t)b * 3 * N_;
    float cx = nxyz[bs * 3 + 0], cy = nxyz[bs * 3 + 1], cz = nxyz[bs * 3 + 2];
    float csq = __fadd_rn(__fadd_rn(__fmul_rn(cx, cx), __fmul_rn(cy, cy)), __fmul_rn(cz, cz));
    const float R2F = (float)(0.45 * 0.45);
    if (tid == 0) cnt = 0;
    __syncthreads();
    for (int j = tid; j < N_; j += 64) {
        float qx = xb[j], qy = xb[N_ + j], qz = xb[2 * N_ + j];
        float psq = __fadd_rn(__fadd_rn(__fmul_rn(qx, qx), __fmul_rn(qy, qy)), __fmul_rn(qz, qz));
        float t = __fmul_rn(cx, qx);
        t = __fmaf_rn(cy, qy, t);
        t = __fmaf_rn(cz, qz, t);
        float d2 = __fsub_rn(__fadd_rn(csq, psq), __fadd_rn(t, t));  // 2*t exact
        float dist = __fsqrt_rn(fmaxf(d2, 0.0f));
        if (dist < R2F) {
            int p = atomicAdd(&cnt, 1);
            if (p < CAP) keys[p] = (((unsigned long long)__float_as_uint(dist)) << 32) | (unsigned)j;
        }
    }
    __syncthreads();
    int nc = cnt; if (nc > CAP) nc = CAP;
    for (int k = 0; k < K_; k++) {
        unsigned long long bk = ~0ull;
        for (int i = tid; i < nc; i += 64) {
            unsigned long long kv = keys[i];
            bk = (kv < bk) ? kv : bk;
        }
        bk = wave_min_u64(bk);
        unsigned int lo = (unsigned int)__builtin_amdgcn_readlane((int)(unsigned int)bk, 63);
        unsigned int hi = (unsigned int)__builtin_amdgcn_readlane((int)(unsigned int)(bk >> 32), 63);
        unsigned long long mk = ((unsigned long long)hi << 32) | lo;
        int j = 0;
        if (mk != ~0ull) {
            j = (int)(mk & 0xffffffffull);
            for (int i = tid; i < nc; i += 64)
                if (keys[i] == mk) keys[i] = ~0ull;
        }
        if (tid == 0) gidx[bs * K_ + k] = j;
    }
}

// ---------------- C1 = W0[:, :3] @ centroid ----------------
__global__ __launch_bounds__(256) void c1_kernel(const float* __restrict__ nxyz,
                                                 const float* __restrict__ W0,
                                                 float* __restrict__ C1) {
    int tid = threadIdx.x; int o = tid & 63, ss = tid >> 6;
    int gs = blockIdx.x * 4 + ss;  // over B*S
    float acc = 0.f;
#pragma unroll
    for (int c = 0; c < 3; c++) acc += W0[o * 67 + c] * nxyz[gs * 3 + c];
    C1[(size_t)gs * 64 + o] = acc;
}

// ---------------- stats of h1 = Q1[g] - C1[s] ----------------
__global__ __launch_bounds__(256) void stats1_kernel(const float* __restrict__ Q1,
                                                     const float* __restrict__ C1,
                                                     const int* __restrict__ gidx,
                                                     double* __restrict__ part) {
    __shared__ double ds1[4][64], ds2[4][64];
    int tid = threadIdx.x; int o = tid & 63, ll = tid >> 6;
    double s1 = 0, s2 = 0;
    for (int it = 0; it < 256; it++) {
        int slot = it * 4096 + blockIdx.x * 4 + ll;
        int b = slot >> 16; int r = slot & 65535; int s = r >> 5;
        int g = gidx[slot];
        float q = Q1[(((size_t)b << 13) + g) * 64 + o];
        float c = C1[((size_t)(b << 11) + s) * 64 + o];
        float h = q - c;
        s1 += h; s2 += (double)h * (double)h;
    }
    ds1[ll][o] = s1; ds2[ll][o] = s2;
    __syncthreads();
    if (tid < 64) {
        double a = 0, bb = 0;
        for (int l = 0; l < 4; l++) { a += ds1[l][tid]; bb += ds2[l][tid]; }
        part[blockIdx.x * 256 + tid * 2] = a;
        part[blockIdx.x * 256 + tid * 2 + 1] = bb;
    }
}

// ---------------- stage-A reduce: 64 blocks, each sums nblocks/64 part rows ----------------
__global__ void stats_reduceA_kernel(const double* __restrict__ part, int nblocks,
                                     double* __restrict__ partA) {
    int per = nblocks >> 6;
    int a = blockIdx.x;
    int c = threadIdx.x;  // 256 threads, one column each
    double s = 0;
    for (int k = 0; k < per; k++)
        s += part[((size_t)(a * per + k)) * 256 + c];
    partA[(size_t)a * 256 + c] = s;
}

// ---------------- stage-B reduce -> affine (a, c); launch with 4*C threads ----------------
__global__ void stats_reduce_kernel(const double* __restrict__ part, int nblocks, int C,
                                    const float* __restrict__ gamma, const float* __restrict__ beta,
                                    float* __restrict__ aff) {
    __shared__ double s1s[512], s2s[512];
    int tid = threadIdx.x;
    int q = tid / C; int o = tid - q * C;
    double s1 = 0, s2 = 0;
    for (int i = q; i < nblocks; i += 4) {
        s1 += part[(size_t)i * 256 + o * 2];
        s2 += part[(size_t)i * 256 + o * 2 + 1];
    }
    s1s[tid] = s1; s2s[tid] = s2;
    __syncthreads();
    if (tid < C) {
        double a1 = s1s[tid] + s1s[tid + C] + s1s[tid + 2 * C] + s1s[tid + 3 * C];
        double a2 = s2s[tid] + s2s[tid + C] + s2s[tid + 2 * C] + s2s[tid + 3 * C];
        const double cnt = 1048576.0;
        double mean = a1 / cnt;
        double var = a2 / cnt - mean * mean; if (var < 0) var = 0;
        double a = (double)gamma[tid] / sqrt(var + EPSBN);
        double c = (double)beta[tid] - a * mean;
        aff[tid] = (float)a; aff[C + tid] = (float)c;
    }
}

// ---------------- layer2 (h2 = W1 @ relu(bn1(h1))) + stats of h2 (no store; codegen untouched) ----------------
__global__ __launch_bounds__(256) void layer2_stats_kernel(const float* __restrict__ Q1,
                                                           const float* __restrict__ C1,
                                                           const int* __restrict__ gidx,
                                                           const float* __restrict__ aff1,
                                                           const float* __restrict__ W1,
                                                           const float* __restrict__ b1,
                                                           double* __restrict__ part) {
    __shared__ __align__(16) float Wl[64 * 64];
    __shared__ float stage[256 * 33 + 8];
    __shared__ float sA[64], sC[64], sB[64];
    __shared__ double r1[8][33], r2[8][33];
    int tid = threadIdx.x;
    for (int i = tid; i < 4096; i += 256) { int o = i >> 6, c = i & 63; Wl[c * 64 + o] = W1[i]; }
    if (tid < 64) { sA[tid] = aff1[tid]; sC[tid] = aff1[64 + tid]; sB[tid] = b1[tid]; }
    __syncthreads();
    int slot = blockIdx.x * 256 + tid;
    int b = slot >> 16; int r = slot & 65535; int s = r >> 5;
    int g = gidx[slot];
    float x[64];
    {
        const float4* qp4 = (const float4*)(Q1 + (((size_t)b << 13) + g) * 64);
        const float4* cp4 = (const float4*)(C1 + ((size_t)(b << 11) + s) * 64);
#pragma unroll
        for (int c4 = 0; c4 < 16; c4++) {
            float4 q = qp4[c4], cc = cp4[c4];
            int c = c4 * 4;
            x[c + 0] = fmaxf(0.f, sA[c + 0] * (q.x - cc.x) + sC[c + 0]);
            x[c + 1] = fmaxf(0.f, sA[c + 1] * (q.y - cc.y) + sC[c + 1]);
            x[c + 2] = fmaxf(0.f, sA[c + 2] * (q.z - cc.z) + sC[c + 2]);
            x[c + 3] = fmaxf(0.f, sA[c + 3] * (q.w - cc.w) + sC[c + 3]);
        }
    }
    const float4* Wl4 = (const float4*)Wl;
    for (int ch = 0; ch < 2; ch++) {
        float acc[32];
#pragma unroll
        for (int o = 0; o < 32; o++) acc[o] = sB[ch * 32 + o];
#pragma unroll
        for (int c = 0; c < 64; c++) {
            float xv = x[c];
#pragma unroll
            for (int og = 0; og < 8; og++) {
                float4 w = Wl4[c * 16 + ch * 8 + og];
                acc[og * 4 + 0] += w.x * xv; acc[og * 4 + 1] += w.y * xv;
                acc[og * 4 + 2] += w.z * xv; acc[og * 4 + 3] += w.w * xv;
            }
        }
#pragma unroll
        for (int o = 0; o < 32; o++) stage[STG(tid, o)] = acc[o];
        __syncthreads();
        int chn = tid & 31, rr = tid >> 5;
        double s1 = 0, s2 = 0;
        for (int row = rr * 32; row < rr * 32 + 32; row++) {
            float v = stage[STG(row, chn)];
            s1 += v; s2 += (double)v * (double)v;
        }
        r1[rr][chn] = s1; r2[rr][chn] = s2;
        __syncthreads();
        if (tid < 32) {
            double a = 0, bb = 0;
            for (int l = 0; l < 8; l++) { a += r1[l][tid]; bb += r2[l][tid]; }
            part[blockIdx.x * 256 + (ch * 32 + tid) * 2] = a;
            part[blockIdx.x * 256 + (ch * 32 + tid) * 2 + 1] = bb;
        }
        __syncthreads();
    }
}

// ---------------- layer2 variant with f16 h2 store (separate kernel; used only on fast path) ----------------
__global__ __launch_bounds__(256) void layer2_stats_store_kernel(const float* __restrict__ Q1,
                                                                 const float* __restrict__ C1,
                                                                 const int* __restrict__ gidx,
                                                                 const float* __restrict__ aff1,
                                                                 const float* __restrict__ W1,
                                                                 const float* __restrict__ b1,
                                                                 double* __restrict__ part,
                                                                 __half* __restrict__ h2out) {
    __shared__ __align__(16) float Wl[64 * 64];
    __shared__ float stage[256 * 33 + 8];
    __shared__ float sA[64], sC[64], sB[64];
    __shared__ double r1[8][33], r2[8][33];
    int tid = threadIdx.x;
    for (int i = tid; i < 4096; i += 256) { int o = i >> 6, c = i & 63; Wl[c * 64 + o] = W1[i]; }
    if (tid < 64) { sA[tid] = aff1[tid]; sC[tid] = aff1[64 + tid]; sB[tid] = b1[tid]; }
    __syncthreads();
    int slot = blockIdx.x * 256 + tid;
    int b = slot >> 16; int r = slot & 65535; int s = r >> 5;
    int g = gidx[slot];
    float x[64];
    {
        const float4* qp4 = (const float4*)(Q1 + (((size_t)b << 13) + g) * 64);
        const float4* cp4 = (const float4*)(C1 + ((size_t)(b << 11) + s) * 64);
#pragma unroll
        for (int c4 = 0; c4 < 16; c4++) {
            float4 q = qp4[c4], cc = cp4[c4];
            int c = c4 * 4;
            x[c + 0] = fmaxf(0.f, sA[c + 0] * (q.x - cc.x) + sC[c + 0]);
            x[c + 1] = fmaxf(0.f, sA[c + 1] * (q.y - cc.y) + sC[c + 1]);
            x[c + 2] = fmaxf(0.f, sA[c + 2] * (q.z - cc.z) + sC[c + 2]);
            x[c + 3] = fmaxf(0.f, sA[c + 3] * (q.w - cc.w) + sC[c + 3]);
        }
    }
    const float4* Wl4 = (const float4*)Wl;
    for (int ch = 0; ch < 2; ch++) {
        float acc[32];
#pragma unroll
        for (int o = 0; o < 32; o++) acc[o] = sB[ch * 32 + o];
#pragma unroll
        for (int c = 0; c < 64; c++) {
            float xv = x[c];
#pragma unroll
            for (int og = 0; og < 8; og++) {
                float4 w = Wl4[c * 16 + ch * 8 + og];
                acc[og * 4 + 0] += w.x * xv; acc[og * 4 + 1] += w.y * xv;
                acc[og * 4 + 2] += w.z * xv; acc[og * 4 + 3] += w.w * xv;
            }
        }
        {
            __half2* o2 = (__half2*)(h2out + ((size_t)slot * 64 + ch * 32));
#pragma unroll
            for (int i = 0; i < 16; i++)
                o2[i] = __floats2half2_rn(acc[2 * i], acc[2 * i + 1]);
        }
#pragma unroll
        for (int o = 0; o < 32; o++) stage[STG(tid, o)] = acc[o];
        __syncthreads();
        int chn = tid & 31, rr = tid >> 5;
        double s1 = 0, s2 = 0;
        for (int row = rr * 32; row < rr * 32 + 32; row++) {
            float v = stage[STG(row, chn)];
            s1 += v; s2 += (double)v * (double)v;
        }
        r1[rr][chn] = s1; r2[rr][chn] = s2;
        __syncthreads();
        if (tid < 32) {
            double a = 0, bb = 0;
            for (int l = 0; l < 8; l++) { a += r1[l][tid]; bb += r2[l][tid]; }
            part[blockIdx.x * 256 + (ch * 32 + tid) * 2] = a;
            part[blockIdx.x * 256 + (ch * 32 + tid) * 2 + 1] = bb;
        }
        __syncthreads();
    }
}

// ---------------- layer3 (slow path): recompute h2 -> x3 -> h3; group-major h3 stores ----------------
__global__ __launch_bounds__(256) void layer3_kernel(const float* __restrict__ Q1,
                                                     const float* __restrict__ C1,
                                                     const int* __restrict__ gidx,
                                                     const float* __restrict__ aff1,
                                                     const float* __restrict__ aff2,
                                                     const float* __restrict__ W1,
                                                     const float* __restrict__ b1,
                                                     const float* __restrict__ W2,
                                                     const float* __restrict__ b2,
                                                     double* __restrict__ part,
                                                     float* __restrict__ h3max,
                                                     float* __restrict__ h3min) {
    __shared__ __align__(16) float Wl[64 * 128];
    __shared__ float stage[256 * 33 + 8];
    __shared__ float sA1[64], sC1[64], sB1[64], sA2[64], sC2[64], sB2[128];
    __shared__ double r1[8][33], r2[8][33];
    int tid = threadIdx.x;
    for (int i = tid; i < 4096; i += 256) { int o = i >> 6, c = i & 63; Wl[c * 64 + o] = W1[i]; }
    if (tid < 64) {
        sA1[tid] = aff1[tid]; sC1[tid] = aff1[64 + tid]; sB1[tid] = b1[tid];
        sA2[tid] = aff2[tid]; sC2[tid] = aff2[64 + tid];
    }
    __syncthreads();
    int slot = blockIdx.x * 256 + tid;
    int b = slot >> 16; int r = slot & 65535; int s = r >> 5;
    int g = gidx[slot];
    float x[64];
    {
        const float4* qp4 = (const float4*)(Q1 + (((size_t)b << 13) + g) * 64);
        const float4* cp4 = (const float4*)(C1 + ((size_t)(b << 11) + s) * 64);
#pragma unroll
        for (int c4 = 0; c4 < 16; c4++) {
            float4 q = qp4[c4], cc = cp4[c4];
            int c = c4 * 4;
            x[c + 0] = fmaxf(0.f, sA1[c + 0] * (q.x - cc.x) + sC1[c + 0]);
            x[c + 1] = fmaxf(0.f, sA1[c + 1] * (q.y - cc.y) + sC1[c + 1]);
            x[c + 2] = fmaxf(0.f, sA1[c + 2] * (q.z - cc.z) + sC1[c + 2]);
            x[c + 3] = fmaxf(0.f, sA1[c + 3] * (q.w - cc.w) + sC1[c + 3]);
        }
    }
    const float4* Wl4 = (const float4*)Wl;
    float x3[64];
    for (int ch = 0; ch < 2; ch++) {
        float acc[32];
#pragma unroll
        for (int o = 0; o < 32; o++) acc[o] = sB1[ch * 32 + o];
#pragma unroll
        for (int c = 0; c < 64; c++) {
            float xv = x[c];
#pragma unroll
            for (int og = 0; og < 8; og++) {
                float4 w = Wl4[c * 16 + ch * 8 + og];
                acc[og * 4 + 0] += w.x * xv; acc[og * 4 + 1] += w.y * xv;
                acc[og * 4 + 2] += w.z * xv; acc[og * 4 + 3] += w.w * xv;
            }
        }
#pragma unroll
        for (int o = 0; o < 32; o++) {
            int oo = ch * 32 + o;
            x3[oo] = fmaxf(0.f, sA2[oo] * acc[o] + sC2[oo]);
        }
    }
    __syncthreads();  // done with W1 region
    for (int i = tid; i < 8192; i += 256) { int o = i >> 6, c = i & 63; Wl[c * 128 + o] = W2[i]; }
    if (tid < 128) sB2[tid] = b2[tid];
    __syncthreads();
    for (int ch = 0; ch < 4; ch++) {
        float acc[32];
#pragma unroll
        for (int o = 0; o < 32; o++) acc[o] = sB2[ch * 32 + o];
#pragma unroll
        for (int c = 0; c < 64; c++) {
            float xv = x3[c];
#pragma unroll
            for (int og = 0; og < 8; og++) {
                float4 w = Wl4[c * 32 + ch * 8 + og];
                acc[og * 4 + 0] += w.x * xv; acc[og * 4 + 1] += w.y * xv;
                acc[og * 4 + 2] += w.z * xv; acc[og * 4 + 3] += w.w * xv;
            }
        }
#pragma unroll
        for (int o = 0; o < 32; o++) stage[STG(tid, o)] = acc[o];
        __syncthreads();
        int chn = tid & 31, rr = tid >> 5;
        double s1 = 0, s2 = 0;
        float mx = -3.402823466e38f, mn = 3.402823466e38f;
        for (int row = rr * 32; row < rr * 32 + 32; row++) {
            float v = stage[STG(row, chn)];
            s1 += v; s2 += (double)v * (double)v;
            mx = fmaxf(mx, v); mn = fminf(mn, v);
        }
        r1[rr][chn] = s1; r2[rr][chn] = s2;
        int gg = blockIdx.x * 8 + rr;
        h3max[(size_t)gg * 128 + ch * 32 + chn] = mx;   // coalesced group-major store
        h3min[(size_t)gg * 128 + ch * 32 + chn] = mn;
        __syncthreads();
        if (tid < 32) {
            double a = 0, bb = 0;
            for (int l = 0; l < 8; l++) { a += r1[l][tid]; bb += r2[l][tid]; }
            part[blockIdx.x * 256 + (ch * 32 + tid) * 2] = a;
            part[blockIdx.x * 256 + (ch * 32 + tid) * 2 + 1] = bb;
        }
        __syncthreads();
    }
}

// ---------------- layer3 fast path: read f16 h2 -> x3 -> W2 phase; group-major h3 stores ----------------
__global__ __launch_bounds__(256) void layer3_fast_kernel(const __half* __restrict__ h2in,
                                                          const float* __restrict__ aff2,
                                                          const float* __restrict__ W2,
                                                          const float* __restrict__ b2,
                                                          double* __restrict__ part,
                                                          float* __restrict__ h3max,
                                                          float* __restrict__ h3min) {
    __shared__ __align__(16) float Wl[64 * 128];
    __shared__ float stage[256 * 33 + 8];
    __shared__ float sA2[64], sC2[64], sB2[128];
    __shared__ double r1[8][33], r2[8][33];
    int tid = threadIdx.x;
    for (int i = tid; i < 8192; i += 256) { int o = i >> 6, c = i & 63; Wl[c * 128 + o] = W2[i]; }
    if (tid < 64) { sA2[tid] = aff2[tid]; sC2[tid] = aff2[64 + tid]; }
    if (tid < 128) sB2[tid] = b2[tid];
    __syncthreads();
    int slot = blockIdx.x * 256 + tid;
    float x3[64];
    {
        const __half2* hp = (const __half2*)(h2in + (size_t)slot * 64);
#pragma unroll
        for (int c2 = 0; c2 < 32; c2++) {
            float2 f = __half22float2(hp[c2]);
            int c = c2 * 2;
            x3[c + 0] = fmaxf(0.f, sA2[c + 0] * f.x + sC2[c + 0]);
            x3[c + 1] = fmaxf(0.f, sA2[c + 1] * f.y + sC2[c + 1]);
        }
    }
    const float4* Wl4 = (const float4*)Wl;
    for (int ch = 0; ch < 4; ch++) {
        float acc[32];
#pragma unroll
        for (int o = 0; o < 32; o++) acc[o] = sB2[ch * 32 + o];
#pragma unroll
        for (int c = 0; c < 64; c++) {
            float xv = x3[c];
#pragma unroll
            for (int og = 0; og < 8; og++) {
                float4 w = Wl4[c * 32 + ch * 8 + og];
                acc[og * 4 + 0] += w.x * xv; acc[og * 4 + 1] += w.y * xv;
                acc[og * 4 + 2] += w.z * xv; acc[og * 4 + 3] += w.w * xv;
            }
        }
#pragma unroll
        for (int o = 0; o < 32; o++) stage[STG(tid, o)] = acc[o];
        __syncthreads();
        int chn = tid & 31, rr = tid >> 5;
        double s1 = 0, s2 = 0;
        float mx = -3.402823466e38f, mn = 3.402823466e38f;
        for (int row = rr * 32; row < rr * 32 + 32; row++) {
            float v = stage[STG(row, chn)];
            s1 += v; s2 += (double)v * (double)v;
            mx = fmaxf(mx, v); mn = fminf(mn, v);
        }
        r1[rr][chn] = s1; r2[rr][chn] = s2;
        int gg = blockIdx.x * 8 + rr;
        h3max[(size_t)gg * 128 + ch * 32 + chn] = mx;
        h3min[(size_t)gg * 128 + ch * 32 + chn] = mn;
        __syncthreads();
        if (tid < 32) {
            double a = 0, bb = 0;
            for (int l = 0; l < 8; l++) { a += r1[l][tid]; bb += r2[l][tid]; }
            part[blockIdx.x * 256 + (ch * 32 + tid) * 2] = a;
            part[blockIdx.x * 256 + (ch * 32 + tid) * 2 + 1] = bb;
        }
        __syncthreads();
    }
}

// ---------------- final v2: coalesced read of group-major h3; LDS transpose; 64B-run writes ----------------
__global__ __launch_bounds__(256) void final_kernel(const float* __restrict__ h3max,
                                                    const float* __restrict__ h3min,
                                                    const float* __restrict__ aff3,
                                                    float* __restrict__ out1) {
    __shared__ float tmx[128][17], tmn[128][17];
    __shared__ float sA3[128], sC3[128];
    int tid = threadIdx.x;
    int gg0 = blockIdx.x * 16;        // 16 groups per block, all in same batch b
    if (tid < 128) { sA3[tid] = aff3[tid]; sC3[tid] = aff3[128 + tid]; }
#pragma unroll
    for (int e = 0; e < 8; e++) {
        int t = e * 256 + tid;         // 0..2047
        int gl = t >> 7, c = t & 127;
        tmx[c][gl] = h3max[(size_t)gg0 * 128 + t];   // consecutive t -> coalesced
        tmn[c][gl] = h3min[(size_t)gg0 * 128 + t];
    }
    __syncthreads();
    int b = gg0 >> 11;
    int ss0 = gg0 & 2047;
#pragma unroll
    for (int e = 0; e < 8; e++) {
        int t = e * 256 + tid;
        int c = t >> 4, gl = t & 15;
        float a = sA3[c], cv = sC3[c];
        float v = (a >= 0.f) ? tmx[c][gl] : tmn[c][gl];
        out1[((size_t)b * 128 + c) * 2048 + ss0 + gl] = fmaxf(0.f, a * v + cv);
    }
}

extern "C" void kernel_launch(void* const* d_in, const int* in_sizes, int n_in,
                              void* d_out, int out_size, void* d_ws, size_t ws_size,
                              hipStream_t stream) {
    (void)in_sizes; (void)n_in; (void)out_size;
    const float* xyz = (const float*)d_in[0];
    const float* pts = (const float*)d_in[1];
    const float* W0  = (const float*)d_in[2];
    const float* b0  = (const float*)d_in[3];
    const float* g0  = (const float*)d_in[4];
    const float* be0 = (const float*)d_in[5];
    const float* W1  = (const float*)d_in[6];
    const float* b1  = (const float*)d_in[7];
    const float* g1  = (const float*)d_in[8];
    const float* be1 = (const float*)d_in[9];
    const float* W2  = (const float*)d_in[10];
    const float* b2  = (const float*)d_in[11];
    const float* g2  = (const float*)d_in[12];
    const float* be2 = (const float*)d_in[13];

    char* ws = (char*)d_ws;
    double* partA  = (double*)(ws + OFF_PARTA);
    float*  nxyz   = (float*)(ws + OFF_NEWXYZ);
    int*    gidx   = (int*)(ws + OFF_GIDX);
    float*  Q1     = (float*)(ws + OFF_Q1);
    float*  C1b    = (float*)(ws + OFF_C1);
    double* part   = (double*)(ws + OFF_PART);
    float*  aff1   = (float*)(ws + OFF_AFF1);
    float*  aff2   = (float*)(ws + OFF_AFF2);
    float*  aff3   = (float*)(ws + OFF_AFF3);
    float*  h3mx   = (float*)(ws + OFF_H3MAX);
    float*  h3mn   = (float*)(ws + OFF_H3MIN);
    float*  out0   = (float*)d_out;
    float*  out1   = out0 + B_ * 3 * S_;

    bool useH2 = ws_size >= WS_NEED_H2;
    __half* h2buf = useH2 ? (__half*)(ws + OFF_H2) : (__half*)0;

    fps_kernel<<<16 + 16384, 512, 0, stream>>>(xyz, pts, W0, b0, Q1, nxyz, out0);
    ball_kernel<<<B_ * S_, 64, 0, stream>>>(xyz, nxyz, gidx);
    c1_kernel<<<(B_ * S_) / 4, 256, 0, stream>>>(nxyz, W0, C1b);
    stats1_kernel<<<1024, 256, 0, stream>>>(Q1, C1b, gidx, part);
    stats_reduceA_kernel<<<64, 256, 0, stream>>>(part, 1024, partA);
    stats_reduce_kernel<<<1, 256, 0, stream>>>(partA, 64, 64, g0, be0, aff1);
    if (useH2) {
        layer2_stats_store_kernel<<<4096, 256, 0, stream>>>(Q1, C1b, gidx, aff1, W1, b1, part, h2buf);
    } else {
        layer2_stats_kernel<<<4096, 256, 0, stream>>>(Q1, C1b, gidx, aff1, W1, b1, part);
    }
    stats_reduceA_kernel<<<64, 256, 0, stream>>>(part, 4096, partA);
    stats_reduce_kernel<<<1, 256, 0, stream>>>(partA, 64, 64, g1, be1, aff2);
    if (useH2) {
        layer3_fast_kernel<<<4096, 256, 0, stream>>>(h2buf, aff2, W2, b2, part, h3mx, h3mn);
    } else {
        layer3_kernel<<<4096, 256, 0, stream>>>(Q1, C1b, gidx, aff1, aff2, W1, b1, W2, b2,
                                                part, h3mx, h3mn);
    }
    stats_reduceA_kernel<<<64, 256, 0, stream>>>(part, 4096, partA);
    stats_reduce_kernel<<<1, 512, 0, stream>>>(partA, 64, 128, g2, be2, aff3);
    final_kernel<<<(B_ * S_) / 16, 256, 0, stream>>>(h3mx, h3mn, aff3, out1);
}

// Round 20
// 3033.605 us; speedup vs baseline: 1.1838x; 1.0577x over previous
//
#include <hip/hip_runtime.h>
#include <hip/hip_fp16.h>

#define B_ 16
#define N_ 8192
#define S_ 2048
#define K_ 32
#define EPSBN 1e-5
#define CAP 1024

// workspace offsets (bytes)
#define OFF_PARTA    0ul            // 64*256*8 = 131072 (dead zone)
#define OFF_NEWXYZ   131072ul
#define OFF_GIDX     524288ul
#define OFF_Q1       4718592ul
#define OFF_C1       38273024ul
#define OFF_PART     46661632ul
#define OFF_AFF1     55050240ul
#define OFF_AFF2     55051264ul
#define OFF_AFF3     55052288ul
#define OFF_H3MAX    55053312ul
#define OFF_H3MIN    71830528ul
#define OFF_H2       88607744ul     // 1M*64*2 = 134217728 (f16)
#define WS_NEED_H2   (OFF_H2 + 134217728ul)

#define STG(row, c) ((row)*33 + ((row)>>5) + (c))

// ---- DPP helpers: wave64 u64 reduce to lane 63 (row_shr 1/2/4/8 + row_bcast15/31) ----
template<int CTRL, int RM>
__device__ __forceinline__ unsigned long long dppmove(unsigned long long x) {
    unsigned int lo = (unsigned int)x, hi = (unsigned int)(x >> 32);
    unsigned int lo2 = (unsigned int)__builtin_amdgcn_update_dpp((int)lo, (int)lo, CTRL, RM, 0xf, false);
    unsigned int hi2 = (unsigned int)__builtin_amdgcn_update_dpp((int)hi, (int)hi, CTRL, RM, 0xf, false);
    return ((unsigned long long)hi2 << 32) | lo2;
}
__device__ __forceinline__ unsigned long long wave_max_u64(unsigned long long x) {
    unsigned long long t;
    t = dppmove<0x111, 0xf>(x); x = (t > x) ? t : x;  // row_shr:1
    t = dppmove<0x112, 0xf>(x); x = (t > x) ? t : x;  // row_shr:2
    t = dppmove<0x114, 0xf>(x); x = (t > x) ? t : x;  // row_shr:4
    t = dppmove<0x118, 0xf>(x); x = (t > x) ? t : x;  // row_shr:8
    t = dppmove<0x142, 0xa>(x); x = (t > x) ? t : x;  // row_bcast15 -> rows 1,3
    t = dppmove<0x143, 0xc>(x); x = (t > x) ? t : x;  // row_bcast31 -> rows 2,3
    return x;  // lane 63 holds the max
}
__device__ __forceinline__ unsigned long long wave_min_u64(unsigned long long x) {
    unsigned long long t;
    t = dppmove<0x111, 0xf>(x); x = (t < x) ? t : x;
    t = dppmove<0x112, 0xf>(x); x = (t < x) ? t : x;
    t = dppmove<0x114, 0xf>(x); x = (t < x) ? t : x;
    t = dppmove<0x118, 0xf>(x); x = (t < x) ? t : x;
    t = dppmove<0x142, 0xa>(x); x = (t < x) ? t : x;
    t = dppmove<0x143, 0xc>(x); x = (t < x) ? t : x;
    return x;  // lane 63 holds the min
}

// ---------------- FPS (blocks 0..15; 256 thr, 4 waves, no idle) + fused Q1 (blocks 16+) ----------------
__global__ __launch_bounds__(256) void fps_kernel(const float* __restrict__ xyz,
                                                  const float* __restrict__ pts,
                                                  const float* __restrict__ W0,
                                                  const float* __restrict__ b0,
                                                  float* __restrict__ Q1,
                                                  float* __restrict__ nxyz,
                                                  float* __restrict__ out0) {
    __shared__ float xs[N_], ys[N_], zs[N_];
    __shared__ int farHist[S_];
    __shared__ unsigned long long kq[2][4];
    int tid = threadIdx.x;
    if (blockIdx.x >= 16) {
        // ---- Q1 = W0 @ [xyz;points] + b0 (independent of FPS; fills idle CUs) ----
        int o = tid & 63, jj = tid >> 6;           // 4 points per block
        int blk = blockIdx.x - 16;                  // 0..32767
        int b = blk >> 11;
        int j = ((blk & 2047) << 2) + jj;
        const float* xb = xyz + (size_t)b * 3 * N_;
        const float* pb = pts + (size_t)b * 64 * N_;
        float acc = b0[o];
#pragma unroll
        for (int c = 0; c < 3; c++) acc += W0[o * 67 + c] * xb[c * N_ + j];
#pragma unroll 8
        for (int c = 0; c < 64; c++) acc += W0[o * 67 + 3 + c] * pb[c * N_ + j];
        Q1[(((size_t)b << 13) + j) * 64 + o] = acc;
        return;
    }
    int b = blockIdx.x;
    const float* xb = xyz + (size_t)b * 3 * N_;
    for (int i = tid; i < N_; i += 256) {
        xs[i] = xb[i]; ys[i] = xb[N_ + i]; zs[i] = xb[2 * N_ + i];
    }
    __syncthreads();
    float px[32], py[32], pz[32], d8[32];
#pragma unroll
    for (int k = 0; k < 32; k++) {
        int i = tid + k * 256;
        px[k] = xs[i]; py[k] = ys[i]; pz[k] = zs[i];
        d8[k] = 1e10f;
    }
    int far = 0;
    int w = tid >> 6;
    for (int t = 0; t < S_; t++) {
        if (tid == 0) farHist[t] = far;
        float cx = xs[far], cy = ys[far], cz = zs[far];
        float bv = -1.f; int bk = 0;
#pragma unroll
        for (int k = 0; k < 32; k++) {
            float dx = px[k] - cx, dy = py[k] - cy, dz = pz[k] - cz;
            float d = dx * dx + dy * dy + dz * dz;
            float dd = fminf(d8[k], d); d8[k] = dd;
            if (dd > bv) { bv = dd; bk = k; }   // strict >: smallest k (= smallest idx) wins ties
        }
        int bi = tid + bk * 256;
        unsigned long long kk = (((unsigned long long)__float_as_uint(bv)) << 32)
                              | (unsigned)(8191 - bi);
        kk = wave_max_u64(kk);
        if ((tid & 63) == 63) kq[t & 1][w] = kk;
        __syncthreads();
        int buf = t & 1;
        unsigned long long fk = kq[buf][0];
#pragma unroll
        for (int q = 1; q < 4; q++) { unsigned long long o = kq[buf][q]; fk = (o > fk) ? o : fk; }
        far = 8191 - (int)(fk & 0xffffffffull);
    }
    __syncthreads();
    // fused gather: nxyz + out0
    for (int s = tid; s < S_; s += 256) {
        int idx = farHist[s];
        float x = xs[idx], y = ys[idx], z = zs[idx];
        int g = b * S_ + s;
        nxyz[g * 3 + 0] = x; nxyz[g * 3 + 1] = y; nxyz[g * 3 + 2] = z;
        out0[(b * 3 + 0) * S_ + s] = x;
        out0[(b * 3 + 1) * S_ + s] = y;
        out0[(b * 3 + 2) * S_ + s] = z;
    }
}

// ---------------- ball query: 64-thr blocks; FMA-chain distance; atomic compaction; DPP selection ----------------
__global__ __launch_bounds__(64) void ball_kernel(const float* __restrict__ xyz,
                                                  const float* __restrict__ nxyz,
                                                  int* __restrict__ gidx) {
    __shared__ unsigned long long keys[CAP];
    __shared__ int cnt;
    int bs = blockIdx.x; int b = bs >> 11; int tid = threadIdx.x;
    const float* xb = xyz + (size_t)b * 3 * N_;
    float cx = nxyz[bs * 3 + 0], cy = nxyz[bs * 3 + 1], cz = nxyz[bs * 3 + 2];
    float csq = __fadd_rn(__fadd_rn(__fmul_rn(cx, cx), __fmul_rn(cy, cy)), __fmul_rn(cz, cz));
    const float R2F = (float)(0.45 * 0.45);
    if (tid == 0) cnt = 0;
    __syncthreads();
    for (int j = tid; j < N_; j += 64) {
        float qx = xb[j], qy = xb[N_ + j], qz = xb[2 * N_ + j];
        float psq = __fadd_rn(__fadd_rn(__fmul_rn(qx, qx), __fmul_rn(qy, qy)), __fmul_rn(qz, qz));
        float t = __fmul_rn(cx, qx);
        t = __fmaf_rn(cy, qy, t);
        t = __fmaf_rn(cz, qz, t);
        float d2 = __fsub_rn(__fadd_rn(csq, psq), __fadd_rn(t, t));  // 2*t exact
        float dist = __fsqrt_rn(fmaxf(d2, 0.0f));
        if (dist < R2F) {
            int p = atomicAdd(&cnt, 1);
            if (p < CAP) keys[p] = (((unsigned long long)__float_as_uint(dist)) << 32) | (unsigned)j;
        }
    }
    __syncthreads();
    int nc = cnt; if (nc > CAP) nc = CAP;
    for (int k = 0; k < K_; k++) {
        unsigned long long bk = ~0ull;
        for (int i = tid; i < nc; i += 64) {
            unsigned long long kv = keys[i];
            bk = (kv < bk) ? kv : bk;
        }
        bk = wave_min_u64(bk);
        unsigned int lo = (unsigned int)__builtin_amdgcn_readlane((int)(unsigned int)bk, 63);
        unsigned int hi = (unsigned int)__builtin_amdgcn_readlane((int)(unsigned int)(bk >> 32), 63);
        unsigned long long mk = ((unsigned long long)hi << 32) | lo;
        int j = 0;
        if (mk != ~0ull) {
            j = (int)(mk & 0xffffffffull);
            for (int i = tid; i < nc; i += 64)
                if (keys[i] == mk) keys[i] = ~0ull;
        }
        if (tid == 0) gidx[bs * K_ + k] = j;
    }
}

// ---------------- C1 = W0[:, :3] @ centroid ----------------
__global__ __launch_bounds__(256) void c1_kernel(const float* __restrict__ nxyz,
                                                 const float* __restrict__ W0,
                                                 float* __restrict__ C1) {
    int tid = threadIdx.x; int o = tid & 63, ss = tid >> 6;
    int gs = blockIdx.x * 4 + ss;  // over B*S
    float acc = 0.f;
#pragma unroll
    for (int c = 0; c < 3; c++) acc += W0[o * 67 + c] * nxyz[gs * 3 + c];
    C1[(size_t)gs * 64 + o] = acc;
}

// ---------------- stats of h1 = Q1[g] - C1[s] ----------------
__global__ __launch_bounds__(256) void stats1_kernel(const float* __restrict__ Q1,
                                                     const float* __restrict__ C1,
                                                     const int* __restrict__ gidx,
                                                     double* __restrict__ part) {
    __shared__ double ds1[4][64], ds2[4][64];
    int tid = threadIdx.x; int o = tid & 63, ll = tid >> 6;
    double s1 = 0, s2 = 0;
    for (int it = 0; it < 256; it++) {
        int slot = it * 4096 + blockIdx.x * 4 + ll;
        int b = slot >> 16; int r = slot & 65535; int s = r >> 5;
        int g = gidx[slot];
        float q = Q1[(((size_t)b << 13) + g) * 64 + o];
        float c = C1[((size_t)(b << 11) + s) * 64 + o];
        float h = q - c;
        s1 += h; s2 += (double)h * (double)h;
    }
    ds1[ll][o] = s1; ds2[ll][o] = s2;
    __syncthreads();
    if (tid < 64) {
        double a = 0, bb = 0;
        for (int l = 0; l < 4; l++) { a += ds1[l][tid]; bb += ds2[l][tid]; }
        part[blockIdx.x * 256 + tid * 2] = a;
        part[blockIdx.x * 256 + tid * 2 + 1] = bb;
    }
}

// ---------------- stage-A reduce: 64 blocks, each sums nblocks/64 part rows ----------------
__global__ void stats_reduceA_kernel(const double* __restrict__ part, int nblocks,
                                     double* __restrict__ partA) {
    int per = nblocks >> 6;
    int a = blockIdx.x;
    int c = threadIdx.x;  // 256 threads, one column each
    double s = 0;
    for (int k = 0; k < per; k++)
        s += part[((size_t)(a * per + k)) * 256 + c];
    partA[(size_t)a * 256 + c] = s;
}

// ---------------- stage-B reduce -> affine (a, c); launch with 4*C threads ----------------
__global__ void stats_reduce_kernel(const double* __restrict__ part, int nblocks, int C,
                                    const float* __restrict__ gamma, const float* __restrict__ beta,
                                    float* __restrict__ aff) {
    __shared__ double s1s[512], s2s[512];
    int tid = threadIdx.x;
    int q = tid / C; int o = tid - q * C;
    double s1 = 0, s2 = 0;
    for (int i = q; i < nblocks; i += 4) {
        s1 += part[(size_t)i * 256 + o * 2];
        s2 += part[(size_t)i * 256 + o * 2 + 1];
    }
    s1s[tid] = s1; s2s[tid] = s2;
    __syncthreads();
    if (tid < C) {
        double a1 = s1s[tid] + s1s[tid + C] + s1s[tid + 2 * C] + s1s[tid + 3 * C];
        double a2 = s2s[tid] + s2s[tid + C] + s2s[tid + 2 * C] + s2s[tid + 3 * C];
        const double cnt = 1048576.0;
        double mean = a1 / cnt;
        double var = a2 / cnt - mean * mean; if (var < 0) var = 0;
        double a = (double)gamma[tid] / sqrt(var + EPSBN);
        double c = (double)beta[tid] - a * mean;
        aff[tid] = (float)a; aff[C + tid] = (float)c;
    }
}

// ---------------- layer2 (h2 = W1 @ relu(bn1(h1))) + stats of h2 (no store; codegen untouched) ----------------
__global__ __launch_bounds__(256) void layer2_stats_kernel(const float* __restrict__ Q1,
                                                           const float* __restrict__ C1,
                                                           const int* __restrict__ gidx,
                                                           const float* __restrict__ aff1,
                                                           const float* __restrict__ W1,
                                                           const float* __restrict__ b1,
                                                           double* __restrict__ part) {
    __shared__ __align__(16) float Wl[64 * 64];
    __shared__ float stage[256 * 33 + 8];
    __shared__ float sA[64], sC[64], sB[64];
    __shared__ double r1[8][33], r2[8][33];
    int tid = threadIdx.x;
    for (int i = tid; i < 4096; i += 256) { int o = i >> 6, c = i & 63; Wl[c * 64 + o] = W1[i]; }
    if (tid < 64) { sA[tid] = aff1[tid]; sC[tid] = aff1[64 + tid]; sB[tid] = b1[tid]; }
    __syncthreads();
    int slot = blockIdx.x * 256 + tid;
    int b = slot >> 16; int r = slot & 65535; int s = r >> 5;
    int g = gidx[slot];
    float x[64];
    {
        const float4* qp4 = (const float4*)(Q1 + (((size_t)b << 13) + g) * 64);
        const float4* cp4 = (const float4*)(C1 + ((size_t)(b << 11) + s) * 64);
#pragma unroll
        for (int c4 = 0; c4 < 16; c4++) {
            float4 q = qp4[c4], cc = cp4[c4];
            int c = c4 * 4;
            x[c + 0] = fmaxf(0.f, sA[c + 0] * (q.x - cc.x) + sC[c + 0]);
            x[c + 1] = fmaxf(0.f, sA[c + 1] * (q.y - cc.y) + sC[c + 1]);
            x[c + 2] = fmaxf(0.f, sA[c + 2] * (q.z - cc.z) + sC[c + 2]);
            x[c + 3] = fmaxf(0.f, sA[c + 3] * (q.w - cc.w) + sC[c + 3]);
        }
    }
    const float4* Wl4 = (const float4*)Wl;
    for (int ch = 0; ch < 2; ch++) {
        float acc[32];
#pragma unroll
        for (int o = 0; o < 32; o++) acc[o] = sB[ch * 32 + o];
#pragma unroll
        for (int c = 0; c < 64; c++) {
            float xv = x[c];
#pragma unroll
            for (int og = 0; og < 8; og++) {
                float4 w = Wl4[c * 16 + ch * 8 + og];
                acc[og * 4 + 0] += w.x * xv; acc[og * 4 + 1] += w.y * xv;
                acc[og * 4 + 2] += w.z * xv; acc[og * 4 + 3] += w.w * xv;
            }
        }
#pragma unroll
        for (int o = 0; o < 32; o++) stage[STG(tid, o)] = acc[o];
        __syncthreads();
        int chn = tid & 31, rr = tid >> 5;
        double s1 = 0, s2 = 0;
        for (int row = rr * 32; row < rr * 32 + 32; row++) {
            float v = stage[STG(row, chn)];
            s1 += v; s2 += (double)v * (double)v;
        }
        r1[rr][chn] = s1; r2[rr][chn] = s2;
        __syncthreads();
        if (tid < 32) {
            double a = 0, bb = 0;
            for (int l = 0; l < 8; l++) { a += r1[l][tid]; bb += r2[l][tid]; }
            part[blockIdx.x * 256 + (ch * 32 + tid) * 2] = a;
            part[blockIdx.x * 256 + (ch * 32 + tid) * 2 + 1] = bb;
        }
        __syncthreads();
    }
}

// ---------------- layer2 variant with f16 h2 store (separate kernel; used only on fast path) ----------------
__global__ __launch_bounds__(256) void layer2_stats_store_kernel(const float* __restrict__ Q1,
                                                                 const float* __restrict__ C1,
                                                                 const int* __restrict__ gidx,
                                                                 const float* __restrict__ aff1,
                                                                 const float* __restrict__ W1,
                                                                 const float* __restrict__ b1,
                                                                 double* __restrict__ part,
                                                                 __half* __restrict__ h2out) {
    __shared__ __align__(16) float Wl[64 * 64];
    __shared__ float stage[256 * 33 + 8];
    __shared__ float sA[64], sC[64], sB[64];
    __shared__ double r1[8][33], r2[8][33];
    int tid = threadIdx.x;
    for (int i = tid; i < 4096; i += 256) { int o = i >> 6, c = i & 63; Wl[c * 64 + o] = W1[i]; }
    if (tid < 64) { sA[tid] = aff1[tid]; sC[tid] = aff1[64 + tid]; sB[tid] = b1[tid]; }
    __syncthreads();
    int slot = blockIdx.x * 256 + tid;
    int b = slot >> 16; int r = slot & 65535; int s = r >> 5;
    int g = gidx[slot];
    float x[64];
    {
        const float4* qp4 = (const float4*)(Q1 + (((size_t)b << 13) + g) * 64);
        const float4* cp4 = (const float4*)(C1 + ((size_t)(b << 11) + s) * 64);
#pragma unroll
        for (int c4 = 0; c4 < 16; c4++) {
            float4 q = qp4[c4], cc = cp4[c4];
            int c = c4 * 4;
            x[c + 0] = fmaxf(0.f, sA[c + 0] * (q.x - cc.x) + sC[c + 0]);
            x[c + 1] = fmaxf(0.f, sA[c + 1] * (q.y - cc.y) + sC[c + 1]);
            x[c + 2] = fmaxf(0.f, sA[c + 2] * (q.z - cc.z) + sC[c + 2]);
            x[c + 3] = fmaxf(0.f, sA[c + 3] * (q.w - cc.w) + sC[c + 3]);
        }
    }
    const float4* Wl4 = (const float4*)Wl;
    for (int ch = 0; ch < 2; ch++) {
        float acc[32];
#pragma unroll
        for (int o = 0; o < 32; o++) acc[o] = sB[ch * 32 + o];
#pragma unroll
        for (int c = 0; c < 64; c++) {
            float xv = x[c];
#pragma unroll
            for (int og = 0; og < 8; og++) {
                float4 w = Wl4[c * 16 + ch * 8 + og];
                acc[og * 4 + 0] += w.x * xv; acc[og * 4 + 1] += w.y * xv;
                acc[og * 4 + 2] += w.z * xv; acc[og * 4 + 3] += w.w * xv;
            }
        }
        {
            __half2* o2 = (__half2*)(h2out + ((size_t)slot * 64 + ch * 32));
#pragma unroll
            for (int i = 0; i < 16; i++)
                o2[i] = __floats2half2_rn(acc[2 * i], acc[2 * i + 1]);
        }
#pragma unroll
        for (int o = 0; o < 32; o++) stage[STG(tid, o)] = acc[o];
        __syncthreads();
        int chn = tid & 31, rr = tid >> 5;
        double s1 = 0, s2 = 0;
        for (int row = rr * 32; row < rr * 32 + 32; row++) {
            float v = stage[STG(row, chn)];
            s1 += v; s2 += (double)v * (double)v;
        }
        r1[rr][chn] = s1; r2[rr][chn] = s2;
        __syncthreads();
        if (tid < 32) {
            double a = 0, bb = 0;
            for (int l = 0; l < 8; l++) { a += r1[l][tid]; bb += r2[l][tid]; }
            part[blockIdx.x * 256 + (ch * 32 + tid) * 2] = a;
            part[blockIdx.x * 256 + (ch * 32 + tid) * 2 + 1] = bb;
        }
        __syncthreads();
    }
}

// ---------------- layer3 (slow path): recompute h2 -> x3 -> h3; group-major h3 stores ----------------
__global__ __launch_bounds__(256) void layer3_kernel(const float* __restrict__ Q1,
                                                     const float* __restrict__ C1,
                                                     const int* __restrict__ gidx,
                                                     const float* __restrict__ aff1,
                                                     const float* __restrict__ aff2,
                                                     const float* __restrict__ W1,
                                                     const float* __restrict__ b1,
                                                     const float* __restrict__ W2,
                                                     const float* __restrict__ b2,
                                                     double* __restrict__ part,
                                                     float* __restrict__ h3max,
                                                     float* __restrict__ h3min) {
    __shared__ __align__(16) float Wl[64 * 128];
    __shared__ float stage[256 * 33 + 8];
    __shared__ float sA1[64], sC1[64], sB1[64], sA2[64], sC2[64], sB2[128];
    __shared__ double r1[8][33], r2[8][33];
    int tid = threadIdx.x;
    for (int i = tid; i < 4096; i += 256) { int o = i >> 6, c = i & 63; Wl[c * 64 + o] = W1[i]; }
    if (tid < 64) {
        sA1[tid] = aff1[tid]; sC1[tid] = aff1[64 + tid]; sB1[tid] = b1[tid];
        sA2[tid] = aff2[tid]; sC2[tid] = aff2[64 + tid];
    }
    __syncthreads();
    int slot = blockIdx.x * 256 + tid;
    int b = slot >> 16; int r = slot & 65535; int s = r >> 5;
    int g = gidx[slot];
    float x[64];
    {
        const float4* qp4 = (const float4*)(Q1 + (((size_t)b << 13) + g) * 64);
        const float4* cp4 = (const float4*)(C1 + ((size_t)(b << 11) + s) * 64);
#pragma unroll
        for (int c4 = 0; c4 < 16; c4++) {
            float4 q = qp4[c4], cc = cp4[c4];
            int c = c4 * 4;
            x[c + 0] = fmaxf(0.f, sA1[c + 0] * (q.x - cc.x) + sC1[c + 0]);
            x[c + 1] = fmaxf(0.f, sA1[c + 1] * (q.y - cc.y) + sC1[c + 1]);
            x[c + 2] = fmaxf(0.f, sA1[c + 2] * (q.z - cc.z) + sC1[c + 2]);
            x[c + 3] = fmaxf(0.f, sA1[c + 3] * (q.w - cc.w) + sC1[c + 3]);
        }
    }
    const float4* Wl4 = (const float4*)Wl;
    float x3[64];
    for (int ch = 0; ch < 2; ch++) {
        float acc[32];
#pragma unroll
        for (int o = 0; o < 32; o++) acc[o] = sB1[ch * 32 + o];
#pragma unroll
        for (int c = 0; c < 64; c++) {
            float xv = x[c];
#pragma unroll
            for (int og = 0; og < 8; og++) {
                float4 w = Wl4[c * 16 + ch * 8 + og];
                acc[og * 4 + 0] += w.x * xv; acc[og * 4 + 1] += w.y * xv;
                acc[og * 4 + 2] += w.z * xv; acc[og * 4 + 3] += w.w * xv;
            }
        }
#pragma unroll
        for (int o = 0; o < 32; o++) {
            int oo = ch * 32 + o;
            x3[oo] = fmaxf(0.f, sA2[oo] * acc[o] + sC2[oo]);
        }
    }
    __syncthreads();  // done with W1 region
    for (int i = tid; i < 8192; i += 256) { int o = i >> 6, c = i & 63; Wl[c * 128 + o] = W2[i]; }
    if (tid < 128) sB2[tid] = b2[tid];
    __syncthreads();
    for (int ch = 0; ch < 4; ch++) {
        float acc[32];
#pragma unroll
        for (int o = 0; o < 32; o++) acc[o] = sB2[ch * 32 + o];
#pragma unroll
        for (int c = 0; c < 64; c++) {
            float xv = x3[c];
#pragma unroll
            for (int og = 0; og < 8; og++) {
                float4 w = Wl4[c * 32 + ch * 8 + og];
                acc[og * 4 + 0] += w.x * xv; acc[og * 4 + 1] += w.y * xv;
                acc[og * 4 + 2] += w.z * xv; acc[og * 4 + 3] += w.w * xv;
            }
        }
#pragma unroll
        for (int o = 0; o < 32; o++) stage[STG(tid, o)] = acc[o];
        __syncthreads();
        int chn = tid & 31, rr = tid >> 5;
        double s1 = 0, s2 = 0;
        float mx = -3.402823466e38f, mn = 3.402823466e38f;
        for (int row = rr * 32; row < rr * 32 + 32; row++) {
            float v = stage[STG(row, chn)];
            s1 += v; s2 += (double)v * (double)v;
            mx = fmaxf(mx, v); mn = fminf(mn, v);
        }
        r1[rr][chn] = s1; r2[rr][chn] = s2;
        int gg = blockIdx.x * 8 + rr;
        h3max[(size_t)gg * 128 + ch * 32 + chn] = mx;   // coalesced group-major store
        h3min[(size_t)gg * 128 + ch * 32 + chn] = mn;
        __syncthreads();
        if (tid < 32) {
            double a = 0, bb = 0;
            for (int l = 0; l < 8; l++) { a += r1[l][tid]; bb += r2[l][tid]; }
            part[blockIdx.x * 256 + (ch * 32 + tid) * 2] = a;
            part[blockIdx.x * 256 + (ch * 32 + tid) * 2 + 1] = bb;
        }
        __syncthreads();
    }
}

// ---------------- layer3 fast path: read f16 h2 -> x3 -> W2 phase; group-major h3 stores ----------------
__global__ __launch_bounds__(256) void layer3_fast_kernel(const __half* __restrict__ h2in,
                                                          const float* __restrict__ aff2,
                                                          const float* __restrict__ W2,
                                                          const float* __restrict__ b2,
                                                          double* __restrict__ part,
                                                          float* __restrict__ h3max,
                                                          float* __restrict__ h3min) {
    __shared__ __align__(16) float Wl[64 * 128];
    __shared__ float stage[256 * 33 + 8];
    __shared__ float sA2[64], sC2[64], sB2[128];
    __shared__ double r1[8][33], r2[8][33];
    int tid = threadIdx.x;
    for (int i = tid; i < 8192; i += 256) { int o = i >> 6, c = i & 63; Wl[c * 128 + o] = W2[i]; }
    if (tid < 64) { sA2[tid] = aff2[tid]; sC2[tid] = aff2[64 + tid]; }
    if (tid < 128) sB2[tid] = b2[tid];
    __syncthreads();
    int slot = blockIdx.x * 256 + tid;
    float x3[64];
    {
        const __half2* hp = (const __half2*)(h2in + (size_t)slot * 64);
#pragma unroll
        for (int c2 = 0; c2 < 32; c2++) {
            float2 f = __half22float2(hp[c2]);
            int c = c2 * 2;
            x3[c + 0] = fmaxf(0.f, sA2[c + 0] * f.x + sC2[c + 0]);
            x3[c + 1] = fmaxf(0.f, sA2[c + 1] * f.y + sC2[c + 1]);
        }
    }
    const float4* Wl4 = (const float4*)Wl;
    for (int ch = 0; ch < 4; ch++) {
        float acc[32];
#pragma unroll
        for (int o = 0; o < 32; o++) acc[o] = sB2[ch * 32 + o];
#pragma unroll
        for (int c = 0; c < 64; c++) {
            float xv = x3[c];
#pragma unroll
            for (int og = 0; og < 8; og++) {
                float4 w = Wl4[c * 32 + ch * 8 + og];
                acc[og * 4 + 0] += w.x * xv; acc[og * 4 + 1] += w.y * xv;
                acc[og * 4 + 2] += w.z * xv; acc[og * 4 + 3] += w.w * xv;
            }
        }
#pragma unroll
        for (int o = 0; o < 32; o++) stage[STG(tid, o)] = acc[o];
        __syncthreads();
        int chn = tid & 31, rr = tid >> 5;
        double s1 = 0, s2 = 0;
        float mx = -3.402823466e38f, mn = 3.402823466e38f;
        for (int row = rr * 32; row < rr * 32 + 32; row++) {
            float v = stage[STG(row, chn)];
            s1 += v; s2 += (double)v * (double)v;
            mx = fmaxf(mx, v); mn = fminf(mn, v);
        }
        r1[rr][chn] = s1; r2[rr][chn] = s2;
        int gg = blockIdx.x * 8 + rr;
        h3max[(size_t)gg * 128 + ch * 32 + chn] = mx;
        h3min[(size_t)gg * 128 + ch * 32 + chn] = mn;
        __syncthreads();
        if (tid < 32) {
            double a = 0, bb = 0;
            for (int l = 0; l < 8; l++) { a += r1[l][tid]; bb += r2[l][tid]; }
            part[blockIdx.x * 256 + (ch * 32 + tid) * 2] = a;
            part[blockIdx.x * 256 + (ch * 32 + tid) * 2 + 1] = bb;
        }
        __syncthreads();
    }
}

// ---------------- final v2: coalesced read of group-major h3; LDS transpose; 64B-run writes ----------------
__global__ __launch_bounds__(256) void final_kernel(const float* __restrict__ h3max,
                                                    const float* __restrict__ h3min,
                                                    const float* __restrict__ aff3,
                                                    float* __restrict__ out1) {
    __shared__ float tmx[128][17], tmn[128][17];
    __shared__ float sA3[128], sC3[128];
    int tid = threadIdx.x;
    int gg0 = blockIdx.x * 16;        // 16 groups per block, all in same batch b
    if (tid < 128) { sA3[tid] = aff3[tid]; sC3[tid] = aff3[128 + tid]; }
#pragma unroll
    for (int e = 0; e < 8; e++) {
        int t = e * 256 + tid;         // 0..2047
        int gl = t >> 7, c = t & 127;
        tmx[c][gl] = h3max[(size_t)gg0 * 128 + t];   // consecutive t -> coalesced
        tmn[c][gl] = h3min[(size_t)gg0 * 128 + t];
    }
    __syncthreads();
    int b = gg0 >> 11;
    int ss0 = gg0 & 2047;
#pragma unroll
    for (int e = 0; e < 8; e++) {
        int t = e * 256 + tid;
        int c = t >> 4, gl = t & 15;
        float a = sA3[c], cv = sC3[c];
        float v = (a >= 0.f) ? tmx[c][gl] : tmn[c][gl];
        out1[((size_t)b * 128 + c) * 2048 + ss0 + gl] = fmaxf(0.f, a * v + cv);
    }
}

extern "C" void kernel_launch(void* const* d_in, const int* in_sizes, int n_in,
                              void* d_out, int out_size, void* d_ws, size_t ws_size,
                              hipStream_t stream) {
    (void)in_sizes; (void)n_in; (void)out_size;
    const float* xyz = (const float*)d_in[0];
    const float* pts = (const float*)d_in[1];
    const float* W0  = (const float*)d_in[2];
    const float* b0  = (const float*)d_in[3];
    const float* g0  = (const float*)d_in[4];
    const float* be0 = (const float*)d_in[5];
    const float* W1  = (const float*)d_in[6];
    const float* b1  = (const float*)d_in[7];
    const float* g1  = (const float*)d_in[8];
    const float* be1 = (const float*)d_in[9];
    const float* W2  = (const float*)d_in[10];
    const float* b2  = (const float*)d_in[11];
    const float* g2  = (const float*)d_in[12];
    const float* be2 = (const float*)d_in[13];

    char* ws = (char*)d_ws;
    double* partA  = (double*)(ws + OFF_PARTA);
    float*  nxyz   = (float*)(ws + OFF_NEWXYZ);
    int*    gidx   = (int*)(ws + OFF_GIDX);
    float*  Q1     = (float*)(ws + OFF_Q1);
    float*  C1b    = (float*)(ws + OFF_C1);
    double* part   = (double*)(ws + OFF_PART);
    float*  aff1   = (float*)(ws + OFF_AFF1);
    float*  aff2   = (float*)(ws + OFF_AFF2);
    float*  aff3   = (float*)(ws + OFF_AFF3);
    float*  h3mx   = (float*)(ws + OFF_H3MAX);
    float*  h3mn   = (float*)(ws + OFF_H3MIN);
    float*  out0   = (float*)d_out;
    float*  out1   = out0 + B_ * 3 * S_;

    bool useH2 = ws_size >= WS_NEED_H2;
    __half* h2buf = useH2 ? (__half*)(ws + OFF_H2) : (__half*)0;

    fps_kernel<<<16 + 32768, 256, 0, stream>>>(xyz, pts, W0, b0, Q1, nxyz, out0);
    ball_kernel<<<B_ * S_, 64, 0, stream>>>(xyz, nxyz, gidx);
    c1_kernel<<<(B_ * S_) / 4, 256, 0, stream>>>(nxyz, W0, C1b);
    stats1_kernel<<<1024, 256, 0, stream>>>(Q1, C1b, gidx, part);
    stats_reduceA_kernel<<<64, 256, 0, stream>>>(part, 1024, partA);
    stats_reduce_kernel<<<1, 256, 0, stream>>>(partA, 64, 64, g0, be0, aff1);
    if (useH2) {
        layer2_stats_store_kernel<<<4096, 256, 0, stream>>>(Q1, C1b, gidx, aff1, W1, b1, part, h2buf);
    } else {
        layer2_stats_kernel<<<4096, 256, 0, stream>>>(Q1, C1b, gidx, aff1, W1, b1, part);
    }
    stats_reduceA_kernel<<<64, 256, 0, stream>>>(part, 4096, partA);
    stats_reduce_kernel<<<1, 256, 0, stream>>>(partA, 64, 64, g1, be1, aff2);
    if (useH2) {
        layer3_fast_kernel<<<4096, 256, 0, stream>>>(h2buf, aff2, W2, b2, part, h3mx, h3mn);
    } else {
        layer3_kernel<<<4096, 256, 0, stream>>>(Q1, C1b, gidx, aff1, aff2, W1, b1, W2, b2,
                                                part, h3mx, h3mn);
    }
    stats_reduceA_kernel<<<64, 256, 0, stream>>>(part, 4096, partA);
    stats_reduce_kernel<<<1, 512, 0, stream>>>(partA, 64, 128, g2, be2, aff3);
    final_kernel<<<(B_ * S_) / 16, 256, 0, stream>>>(h3mx, h3mn, aff3, out1);
}